// Round 4
// baseline (8727.798 us; speedup 1.0000x reference)
//
#include <hip/hip_runtime.h>

#define T_NT 4
#define T_R  5
#define T_H  4
#define T_DK 32
#define T_HD 128
#define T_L  2

typedef unsigned short u16;

__device__ __forceinline__ float bf2f(u16 u){
  union { float f; unsigned int i; } v; v.i = ((unsigned int)u) << 16; return v.f;
}
__device__ __forceinline__ u16 f2bf(float f){
  union { float f; unsigned int i; } v; v.f = f;
  unsigned int x = v.i;
  return (u16)((x + 0x7fffu + ((x >> 16) & 1u)) >> 16);
}
__device__ __forceinline__ float gelu_f(float x){
  float x3 = x*x*x;
  return 0.5f * x * (1.f + tanhf(0.7978845608028654f * (x + 0.044715f * x3)));
}

// ---------------- CSR / bucket build (LDS-aggregated, line-padded) ----------------
__global__ void k_hist4(const int* __restrict__ key, int* __restrict__ cnt, int n){
  __shared__ int c[T_NT];
  int tid = threadIdx.x;
  if (tid < T_NT) c[tid] = 0;
  __syncthreads();
  int base = blockIdx.x*1024;
#pragma unroll
  for (int j=0;j<4;j++){
    int i = base + tid + j*256;
    if (i < n) atomicAdd(&c[key[i]], 1);
  }
  __syncthreads();
  if (tid < T_NT) atomicAdd(&cnt[tid], c[tid]);
}

__global__ void k_toff(const int* __restrict__ cnt, int* __restrict__ off, int* __restrict__ tcur){
  if (threadIdx.x == 0){
    off[0] = 0;
    for (int t = 0; t < T_NT; ++t) off[t+1] = off[t] + cnt[t];
    for (int t = 0; t < T_NT; ++t) tcur[t] = off[t];
  }
}

__global__ void k_scatter2(const int* __restrict__ nt, int* __restrict__ tcur,
                           int* __restrict__ perm, int n){
  __shared__ int lc[T_NT], lb[T_NT];
  int tid = threadIdx.x;
  if (tid < T_NT) lc[tid] = 0;
  __syncthreads();
  int base = blockIdx.x*1024;
  int t[4], lr[4];
#pragma unroll
  for (int j=0;j<4;j++){
    int i = base + tid + j*256;
    if (i < n){ t[j] = nt[i]; lr[j] = atomicAdd(&lc[t[j]], 1); }
    else t[j] = -1;
  }
  __syncthreads();
  if (tid < T_NT) lb[tid] = atomicAdd(&tcur[tid], lc[tid]);
  __syncthreads();
#pragma unroll
  for (int j=0;j<4;j++){
    if (t[j] >= 0) perm[lb[t[j]] + lr[j]] = base + tid + j*256;
  }
}

// degree histogram with 64B-padded counters; captures per-edge rank
__global__ void k_deg(const int* __restrict__ dstp, int* __restrict__ degp,
                      int* __restrict__ rank, int n){
  int i = blockIdx.x*256 + threadIdx.x;
  if (i < n) rank[i] = atomicAdd(&degp[(size_t)dstp[i] << 4], 1);
}

// single-block scan: thread-serial chunks + 1024-wide LDS scan
__global__ void k_scan2(const int* __restrict__ degp, int* __restrict__ rp, int n){
  __shared__ int buf[1024];
  int tid = threadIdx.x;
  int ch = (n + 1023) >> 10;
  int lo = tid*ch, hi = lo + ch; if (hi > n) hi = n;
  int s = 0;
  for (int j = lo; j < hi; ++j) s += degp[(size_t)j << 4];
  buf[tid] = s;
  __syncthreads();
  for (int off = 1; off < 1024; off <<= 1){
    int add = (tid >= off) ? buf[tid - off] : 0;
    __syncthreads();
    buf[tid] += add;
    __syncthreads();
  }
  int b = (tid == 0) ? 0 : buf[tid-1];
  for (int j = lo; j < hi; ++j){ rp[j] = b; b += degp[(size_t)j << 4]; }
  if (tid == 1023) rp[n] = buf[1023];
}

// atomic-free edge placement using precomputed ranks
__global__ void k_fill2(const int* __restrict__ srcp, const int* __restrict__ dstp,
                        const int* __restrict__ etp, const int* __restrict__ rp,
                        const int* __restrict__ rank, int* __restrict__ packed, int n){
  int i = blockIdx.x*256 + threadIdx.x;
  if (i < n){
    int d = dstp[i];
    packed[rp[d] + rank[i]] = srcp[i] | (etp[i] << 17);   // N=50000 < 2^17
  }
}

// ---------------- per-type gathered GEMM (f32 in, f32 weights, fp32 accum) ----------------
// MODE: 0 plain, 1 tanh epilogue (adapt), 3 gelu-on-input + gated residual (update)
// OB: 1 -> out bf16 (u16), 0 -> out f32
template<int MODE, int OB>
__global__ __launch_bounds__(256)
void k_typed_gemm(const float* __restrict__ X,
                  const int* __restrict__ tperm, const int* __restrict__ toff,
                  const float* __restrict__ W, const float* __restrict__ Bi,
                  void* __restrict__ outv,
                  const float* __restrict__ h_in, const float* __restrict__ skipv)
{
  int t = blockIdx.y;
  int lo = toff[t], cnt = toff[t+1] - lo;
  int base = (int)blockIdx.x * 64;
  if (base >= cnt) return;
  __shared__ float As[64][16];
  __shared__ float Bs[16][128];
  __shared__ int rows_s[64];
  int tid = threadIdx.x;
  if (tid < 64){
    int m = base + tid;
    rows_s[tid] = (m < cnt) ? tperm[lo + m] : -1;
  }
  __syncthreads();
  float acc[8][4];
#pragma unroll
  for (int i=0;i<8;i++){ acc[i][0]=0.f;acc[i][1]=0.f;acc[i][2]=0.f;acc[i][3]=0.f; }
  int ty = tid >> 5, tx = tid & 31;
  const float* Wt = W + (size_t)t * (T_HD*T_HD);
  for (int k0 = 0; k0 < T_HD; k0 += 16){
#pragma unroll
    for (int j=0;j<4;j++){
      int idx = tid + j*256;
      int m = idx >> 4, kk = idx & 15;
      int row = rows_s[m];
      float v = 0.f;
      if (row >= 0){
        v = X[(size_t)row*T_HD + k0 + kk];
        if (MODE == 3) v = gelu_f(v);
      }
      As[m][kk] = v;
    }
#pragma unroll
    for (int j=0;j<8;j++){
      int idx = tid + j*256;
      int kk = idx >> 7, c = idx & 127;
      Bs[kk][c] = Wt[(size_t)(k0+kk)*T_HD + c];
    }
    __syncthreads();
#pragma unroll
    for (int kk=0;kk<16;kk++){
      float4 bv = *(const float4*)&Bs[kk][tx*4];
#pragma unroll
      for (int i=0;i<8;i++){
        float a = As[ty*8+i][kk];
        acc[i][0] += a*bv.x; acc[i][1] += a*bv.y; acc[i][2] += a*bv.z; acc[i][3] += a*bv.w;
      }
    }
    __syncthreads();
  }
  float sk = 0.f;
  if (MODE == 3) sk = 1.f / (1.f + __expf(-skipv[t]));
#pragma unroll
  for (int i=0;i<8;i++){
    int m = ty*8 + i;
    int row = rows_s[m];
    if (row < 0) continue;
#pragma unroll
    for (int q=0;q<4;q++){
      int c = tx*4 + q;
      float vv = acc[i][q] + Bi[t*T_HD + c];
      if (MODE == 1) vv = tanhf(vv);
      if (MODE == 3) vv = vv*sk + h_in[(size_t)row*T_HD + c]*(1.f - sk);
      if (OB) ((u16*)outv)[(size_t)row*T_HD + c] = f2bf(vv);
      else    ((float*)outv)[(size_t)row*T_HD + c] = vv;
    }
  }
}

// ---------------- per-node block-diagonal transform, v2 ----------------
// thread = (4 nodes, 1 head), owns all 32 outputs of its head.
// TR=1 (qt): out[n,r,h,i] = sum_j X[n,h*32+j] * Wg[r,h,i,j]
// TR=0 (mtp): out[n,r,h,j] = sum_i X[n,h*32+i] * Wg[r,h,i,j]
template<int TR>
__global__ __launch_bounds__(256, 2)
void k_blockdiag2(const u16* __restrict__ X, const float* __restrict__ Wg,
                  u16* __restrict__ Y, int n)
{
  const int WS_C = 36;      // words per contraction index (16B-aligned, bank-spread)
  const int WS_H = 1160;    // words per head (16B-aligned, == 8 mod 32)
  __shared__ float Ws[T_H * WS_H];
  int r = blockIdx.y;
  int tid = threadIdx.x;
  // stage W into LDS, layout Ws[h][c][o] (c = contraction index)
#pragma unroll
  for (int k = 0; k < 16; ++k){
    int idx = tid + k*256;
    int a = idx & 31;            // contiguous (last) index j of Wg[r][h][i][j]
    int b = (idx >> 5) & 31;     // index i
    int h = idx >> 10;
    float wv = Wg[(((size_t)r*T_H + h)*T_DK + b)*T_DK + a];
    if (TR) Ws[h*WS_H + a*WS_C + b] = wv;   // c=j, o=i
    else    Ws[h*WS_H + b*WS_C + a] = wv;   // c=i, o=j
  }
  int h = tid & 3, p = tid >> 2;
  int base = (int)blockIdx.x * 256;
  uint4 xq[4][4];
  int nodes[4];
#pragma unroll
  for (int m = 0; m < 4; ++m){
    int node = base + m*64 + p;
    nodes[m] = node;
    if (node < n){
#pragma unroll
      for (int k = 0; k < 4; ++k)
        xq[m][k] = *(const uint4*)&X[(size_t)node*T_HD + h*T_DK + k*8];
    } else {
#pragma unroll
      for (int k = 0; k < 4; ++k) xq[m][k] = make_uint4(0,0,0,0);
    }
  }
  __syncthreads();
  float4 acc[4][8];
#pragma unroll
  for (int m=0;m<4;m++)
#pragma unroll
    for (int og=0;og<8;og++) acc[m][og] = make_float4(0.f,0.f,0.f,0.f);
  const float* Wh = &Ws[h*WS_H];
#pragma unroll
  for (int c = 0; c < 32; ++c){
    float xv[4];
#pragma unroll
    for (int m=0;m<4;m++){
      unsigned int w = ((const unsigned int*)&xq[m][0])[c>>1];
      xv[m] = (c&1) ? __uint_as_float(w & 0xffff0000u) : __uint_as_float(w << 16);
    }
#pragma unroll
    for (int og = 0; og < 8; ++og){
      float4 w4 = *(const float4*)&Wh[c*WS_C + og*4];
#pragma unroll
      for (int m=0;m<4;m++){
        acc[m][og].x += xv[m]*w4.x;
        acc[m][og].y += xv[m]*w4.y;
        acc[m][og].z += xv[m]*w4.z;
        acc[m][og].w += xv[m]*w4.w;
      }
    }
  }
#pragma unroll
  for (int m=0;m<4;m++){
    if (nodes[m] < n){
      u16* yb = &Y[(size_t)nodes[m]*(T_R*T_HD) + (size_t)r*T_HD + h*T_DK];
#pragma unroll
      for (int og=0; og<8; og+=2){
        uint4 o4;
        o4.x = (unsigned int)f2bf(acc[m][og].x)   | ((unsigned int)f2bf(acc[m][og].y)   << 16);
        o4.y = (unsigned int)f2bf(acc[m][og].z)   | ((unsigned int)f2bf(acc[m][og].w)   << 16);
        o4.z = (unsigned int)f2bf(acc[m][og+1].x) | ((unsigned int)f2bf(acc[m][og+1].y) << 16);
        o4.w = (unsigned int)f2bf(acc[m][og+1].z) | ((unsigned int)f2bf(acc[m][og+1].w) << 16);
        *(uint4*)&yb[og*4] = o4;
      }
    }
  }
}

// ---------------- per-dst edge attention (one wave per dst, online softmax) ----------------
__global__ __launch_bounds__(256)
void k_edge_attn(const u16* __restrict__ kB, const u16* __restrict__ qt,
                 const u16* __restrict__ mtp, const int* __restrict__ rp,
                 const int* __restrict__ packed, const float* __restrict__ pri,
                 float* __restrict__ resb, int n)
{
  int lane = threadIdx.x & 63;
  int wid = (int)blockIdx.x * (blockDim.x >> 6) + (threadIdx.x >> 6);
  int nw = (int)gridDim.x * (blockDim.x >> 6);
  int h1 = lane >> 5;           // head of first half: 0/1; second half head = h1+2
  const float isd = 0.17677669529663687f;
  float pr1[T_R], pr2[T_R];
#pragma unroll
  for (int r=0;r<T_R;r++){
    pr1[r] = pri[r*T_H + h1] * isd;
    pr2[r] = pri[r*T_H + h1 + 2] * isd;
  }
  for (int dst = wid; dst < n; dst += nw){
    int e0 = rp[dst], e1 = rp[dst+1];
    size_t qbase = (size_t)dst * (T_R*T_HD);
    float u1[T_R], u2[T_R];
#pragma unroll
    for (int r=0;r<T_R;r++){
      u1[r] = bf2f(qt[qbase + r*T_HD + lane]);
      u2[r] = bf2f(qt[qbase + r*T_HD + 64 + lane]);
    }
    float m1=-INFINITY, m2=-INFINITY, d1=0.f, d2=0.f, a1=0.f, a2=0.f;
    for (int ei=e0; ei<e1; ++ei){
      int pk = packed[ei];
      int s = pk & 131071;
      int rt = pk >> 17;
      float ka = bf2f(kB[(size_t)s*T_HD + lane]);
      float kb = bf2f(kB[(size_t)s*T_HD + 64 + lane]);
      float ua, ub, pa, pb;
      switch(rt){
        case 0: ua=u1[0]; ub=u2[0]; pa=pr1[0]; pb=pr2[0]; break;
        case 1: ua=u1[1]; ub=u2[1]; pa=pr1[1]; pb=pr2[1]; break;
        case 2: ua=u1[2]; ub=u2[2]; pa=pr1[2]; pb=pr2[2]; break;
        case 3: ua=u1[3]; ub=u2[3]; pa=pr1[3]; pb=pr2[3]; break;
        default:ua=u1[4]; ub=u2[4]; pa=pr1[4]; pb=pr2[4]; break;
      }
      float p1 = ua*ka, p2 = ub*kb;
#pragma unroll
      for (int o=16;o>=1;o>>=1){
        p1 += __shfl_xor(p1, o, 32);
        p2 += __shfl_xor(p2, o, 32);
      }
      float s1 = p1*pa, s2 = p2*pb;
      size_t mb = (size_t)s*(T_R*T_HD) + (size_t)rt*T_HD;
      float ma = bf2f(mtp[mb + lane]);
      float mv = bf2f(mtp[mb + 64 + lane]);
      float mn1 = fmaxf(m1, s1), mn2 = fmaxf(m2, s2);
      float sc1 = __expf(m1 - mn1), sc2 = __expf(m2 - mn2);
      float w1 = __expf(s1 - mn1), w2 = __expf(s2 - mn2);
      m1 = mn1; m2 = mn2;
      d1 = d1*sc1 + w1; d2 = d2*sc2 + w2;
      a1 = a1*sc1 + w1*ma; a2 = a2*sc2 + w2*mv;
    }
    float i1 = 1.f / fmaxf(d1, 1e-9f);
    float i2 = 1.f / fmaxf(d2, 1e-9f);
    resb[(size_t)dst*T_HD + lane]      = a1 * i1;
    resb[(size_t)dst*T_HD + 64 + lane] = a2 * i2;
  }
}

extern "C" void kernel_launch(void* const* d_in, const int* in_sizes, int n_in,
                              void* d_out, int out_size, void* d_ws, size_t ws_size,
                              hipStream_t stream)
{
  const float* node_feature = (const float*)d_in[0];
  const int* node_type    = (const int*)d_in[1];
  // d_in[2] edge_time: unused by the reference
  const int* edge_index   = (const int*)d_in[3];
  const int* edge_type    = (const int*)d_in[4];
  const float* adapt_w = (const float*)d_in[5];
  const float* adapt_b = (const float*)d_in[6];
  const float* kw = (const float*)d_in[7];
  const float* kb = (const float*)d_in[8];
  const float* qw = (const float*)d_in[9];
  const float* qb = (const float*)d_in[10];
  const float* vw = (const float*)d_in[11];
  const float* vb = (const float*)d_in[12];
  const float* aw = (const float*)d_in[13];
  const float* ab = (const float*)d_in[14];
  const float* rel_pri = (const float*)d_in[15];
  const float* rel_att = (const float*)d_in[16];
  const float* rel_msg = (const float*)d_in[17];
  const float* skipp   = (const float*)d_in[18];

  const int N = in_sizes[1];
  const int E = in_sizes[4];
  const int* srcp = edge_index;
  const int* dstp = edge_index + E;

  char* p = (char*)d_ws;
  auto take = [&](size_t bytes)->char*{
    char* r = p; p += (bytes + 255) & ~(size_t)255; return r;
  };
  float* h0   = (float*)take((size_t)N*T_HD*4);      // 25.6 MB f32 features
  u16*  kB    = (u16*) take((size_t)N*T_HD*2);       // 12.8 MB
  u16*  qB    = (u16*) take((size_t)N*T_HD*2);       // 12.8 MB
  u16*  vB    = (u16*) take((size_t)N*T_HD*2);       // 12.8 MB (contiguous with qB)
  float* resb = (float*)qB;                          // alias qB+vB (dead once qt/mtp built)
  u16*  qt    = (u16*) take((size_t)N*T_R*T_HD*2);   // 64 MB
  u16*  mtp   = (u16*) take((size_t)N*T_R*T_HD*2);   // 64 MB
  int* degp   = (int*) take((size_t)N*16*4);         // 3.2 MB line-padded counters
  int* rp     = (int*) take(((size_t)N+1)*4);
  int* rank   = (int*) take((size_t)E*4);
  int* packed = (int*) take((size_t)E*4);
  int* tcnt   = (int*) take(256);
  int* toff   = (int*) take(256);
  int* tcur   = (int*) take(256);
  int* tperm  = (int*) take((size_t)N*4);

  hipMemsetAsync(degp, 0, (size_t)N*16*4, stream);
  hipMemsetAsync(tcnt, 0, 256, stream);

  int nb_n4 = (N + 1023)/1024, nb_e = (E + 255)/256;
  k_hist4<<<nb_n4, 256, 0, stream>>>(node_type, tcnt, N);
  k_deg<<<nb_e, 256, 0, stream>>>(dstp, degp, rank, E);
  k_toff<<<1, 64, 0, stream>>>(tcnt, toff, tcur);
  k_scan2<<<1, 1024, 0, stream>>>(degp, rp, N);
  k_scatter2<<<nb_n4, 256, 0, stream>>>(node_type, tcur, tperm, N);
  k_fill2<<<nb_e, 256, 0, stream>>>(srcp, dstp, edge_type, rp, rank, packed, E);

  dim3 gg((N + 63)/64, T_NT);
  dim3 gb2((N + 255)/256, T_R);
  // adapt: h0 = tanh(node_feature @ adapt_w[t] + adapt_b[t])
  k_typed_gemm<1,0><<<gg, 256, 0, stream>>>(node_feature, tperm, toff, adapt_w, adapt_b, h0, nullptr, nullptr);

  for (int l = 0; l < T_L; ++l){
    size_t wo = (size_t)l * T_NT * T_HD * T_HD;
    size_t bo = (size_t)l * T_NT * T_HD;
    size_t ro = (size_t)l * T_R * T_H * T_DK * T_DK;
    k_typed_gemm<0,1><<<gg, 256, 0, stream>>>(h0, tperm, toff, kw+wo, kb+bo, kB, nullptr, nullptr);
    k_typed_gemm<0,1><<<gg, 256, 0, stream>>>(h0, tperm, toff, qw+wo, qb+bo, qB, nullptr, nullptr);
    k_typed_gemm<0,1><<<gg, 256, 0, stream>>>(h0, tperm, toff, vw+wo, vb+bo, vB, nullptr, nullptr);
    k_blockdiag2<1><<<gb2, 256, 0, stream>>>(qB, rel_att + ro, qt, N);   // qt[n,r,h,i] = sum_j A[r,h,i,j] q[n,h,j]
    k_blockdiag2<0><<<gb2, 256, 0, stream>>>(vB, rel_msg + ro, mtp, N);  // mtp[n,r,h,j] = sum_i v[n,h,i] M[r,h,i,j]
    k_edge_attn<<<2048, 256, 0, stream>>>(kB, qt, mtp, rp, packed, rel_pri + (size_t)l*T_R*T_H, resb, N);
    if (l == T_L - 1)
      k_typed_gemm<3,0><<<gg, 256, 0, stream>>>(resb, tperm, toff, aw+wo, ab+bo, d_out, h0, skipp + l*T_NT);
    else
      k_typed_gemm<3,0><<<gg, 256, 0, stream>>>(resb, tperm, toff, aw+wo, ab+bo, h0, h0, skipp + l*T_NT);
  }
}

// Round 5
// 933.008 us; speedup vs baseline: 9.3545x; 9.3545x over previous
//
#include <hip/hip_runtime.h>

#define T_NT 4
#define T_R  5
#define T_H  4
#define T_DK 32
#define T_HD 128
#define T_L  2

typedef unsigned short u16;

__device__ __forceinline__ float bf2f(u16 u){
  union { float f; unsigned int i; } v; v.i = ((unsigned int)u) << 16; return v.f;
}
__device__ __forceinline__ u16 f2bf(float f){
  union { float f; unsigned int i; } v; v.f = f;
  unsigned int x = v.i;
  return (u16)((x + 0x7fffu + ((x >> 16) & 1u)) >> 16);
}
__device__ __forceinline__ float gelu_f(float x){
  float x3 = x*x*x;
  return 0.5f * x * (1.f + tanhf(0.7978845608028654f * (x + 0.044715f * x3)));
}

// ---------------- CSR / bucket build (LDS-aggregated, line-padded) ----------------
__global__ void k_hist4(const int* __restrict__ key, int* __restrict__ cnt, int n){
  __shared__ int c[T_NT];
  int tid = threadIdx.x;
  if (tid < T_NT) c[tid] = 0;
  __syncthreads();
  int base = blockIdx.x*1024;
#pragma unroll
  for (int j=0;j<4;j++){
    int i = base + tid + j*256;
    if (i < n) atomicAdd(&c[key[i]], 1);
  }
  __syncthreads();
  if (tid < T_NT) atomicAdd(&cnt[tid], c[tid]);
}

__global__ void k_toff(const int* __restrict__ cnt, int* __restrict__ off, int* __restrict__ tcur){
  if (threadIdx.x == 0){
    off[0] = 0;
    for (int t = 0; t < T_NT; ++t) off[t+1] = off[t] + cnt[t];
    for (int t = 0; t < T_NT; ++t) tcur[t] = off[t];
  }
}

__global__ void k_scatter2(const int* __restrict__ nt, int* __restrict__ tcur,
                           int* __restrict__ perm, int n){
  __shared__ int lc[T_NT], lb[T_NT];
  int tid = threadIdx.x;
  if (tid < T_NT) lc[tid] = 0;
  __syncthreads();
  int base = blockIdx.x*1024;
  int t[4], lr[4];
#pragma unroll
  for (int j=0;j<4;j++){
    int i = base + tid + j*256;
    if (i < n){ t[j] = nt[i]; lr[j] = atomicAdd(&lc[t[j]], 1); }
    else t[j] = -1;
  }
  __syncthreads();
  if (tid < T_NT) lb[tid] = atomicAdd(&tcur[tid], lc[tid]);
  __syncthreads();
#pragma unroll
  for (int j=0;j<4;j++){
    if (t[j] >= 0) perm[lb[t[j]] + lr[j]] = base + tid + j*256;
  }
}

// degree histogram with 64B-padded counters; captures per-edge rank
__global__ void k_deg(const int* __restrict__ dstp, int* __restrict__ degp,
                      int* __restrict__ rank, int n){
  int i = blockIdx.x*256 + threadIdx.x;
  if (i < n) rank[i] = atomicAdd(&degp[(size_t)dstp[i] << 4], 1);
}

// single-block scan: thread-serial chunks + 1024-wide LDS scan
__global__ void k_scan2(const int* __restrict__ degp, int* __restrict__ rp, int n){
  __shared__ int buf[1024];
  int tid = threadIdx.x;
  int ch = (n + 1023) >> 10;
  int lo = tid*ch, hi = lo + ch; if (hi > n) hi = n;
  int s = 0;
  for (int j = lo; j < hi; ++j) s += degp[(size_t)j << 4];
  buf[tid] = s;
  __syncthreads();
  for (int off = 1; off < 1024; off <<= 1){
    int add = (tid >= off) ? buf[tid - off] : 0;
    __syncthreads();
    buf[tid] += add;
    __syncthreads();
  }
  int b = (tid == 0) ? 0 : buf[tid-1];
  for (int j = lo; j < hi; ++j){ rp[j] = b; b += degp[(size_t)j << 4]; }
  if (tid == 1023) rp[n] = buf[1023];
}

// atomic-free edge placement using precomputed ranks
__global__ void k_fill2(const int* __restrict__ srcp, const int* __restrict__ dstp,
                        const int* __restrict__ etp, const int* __restrict__ rp,
                        const int* __restrict__ rank, int* __restrict__ packed, int n){
  int i = blockIdx.x*256 + threadIdx.x;
  if (i < n){
    int d = dstp[i];
    packed[rp[d] + rank[i]] = srcp[i] | (etp[i] << 17);   // N=50000 < 2^17
  }
}

// ---------------- per-type gathered GEMM (f32 in, f32 weights, fp32 accum) ----------------
// MODE: 0 plain, 1 tanh epilogue (adapt), 3 gelu-on-input + gated residual (update)
// OB: 1 -> out bf16 (u16), 0 -> out f32
template<int MODE, int OB>
__global__ __launch_bounds__(256)
void k_typed_gemm(const float* __restrict__ X,
                  const int* __restrict__ tperm, const int* __restrict__ toff,
                  const float* __restrict__ W, const float* __restrict__ Bi,
                  void* __restrict__ outv,
                  const float* __restrict__ h_in, const float* __restrict__ skipv)
{
  int t = blockIdx.y;
  int lo = toff[t], cnt = toff[t+1] - lo;
  int base = (int)blockIdx.x * 64;
  if (base >= cnt) return;
  __shared__ float As[64][16];
  __shared__ float Bs[16][128];
  __shared__ int rows_s[64];
  int tid = threadIdx.x;
  if (tid < 64){
    int m = base + tid;
    rows_s[tid] = (m < cnt) ? tperm[lo + m] : -1;
  }
  __syncthreads();
  float acc[8][4];
#pragma unroll
  for (int i=0;i<8;i++){ acc[i][0]=0.f;acc[i][1]=0.f;acc[i][2]=0.f;acc[i][3]=0.f; }
  int ty = tid >> 5, tx = tid & 31;
  const float* Wt = W + (size_t)t * (T_HD*T_HD);
  for (int k0 = 0; k0 < T_HD; k0 += 16){
#pragma unroll
    for (int j=0;j<4;j++){
      int idx = tid + j*256;
      int m = idx >> 4, kk = idx & 15;
      int row = rows_s[m];
      float v = 0.f;
      if (row >= 0){
        v = X[(size_t)row*T_HD + k0 + kk];
        if (MODE == 3) v = gelu_f(v);
      }
      As[m][kk] = v;
    }
#pragma unroll
    for (int j=0;j<8;j++){
      int idx = tid + j*256;
      int kk = idx >> 7, c = idx & 127;
      Bs[kk][c] = Wt[(size_t)(k0+kk)*T_HD + c];
    }
    __syncthreads();
#pragma unroll
    for (int kk=0;kk<16;kk++){
      float4 bv = *(const float4*)&Bs[kk][tx*4];
#pragma unroll
      for (int i=0;i<8;i++){
        float a = As[ty*8+i][kk];
        acc[i][0] += a*bv.x; acc[i][1] += a*bv.y; acc[i][2] += a*bv.z; acc[i][3] += a*bv.w;
      }
    }
    __syncthreads();
  }
  float sk = 0.f;
  if (MODE == 3) sk = 1.f / (1.f + __expf(-skipv[t]));
#pragma unroll
  for (int i=0;i<8;i++){
    int m = ty*8 + i;
    int row = rows_s[m];
    if (row < 0) continue;
#pragma unroll
    for (int q=0;q<4;q++){
      int c = tx*4 + q;
      float vv = acc[i][q] + Bi[t*T_HD + c];
      if (MODE == 1) vv = tanhf(vv);
      if (MODE == 3) vv = vv*sk + h_in[(size_t)row*T_HD + c]*(1.f - sk);
      if (OB) ((u16*)outv)[(size_t)row*T_HD + c] = f2bf(vv);
      else    ((float*)outv)[(size_t)row*T_HD + c] = vv;
    }
  }
}

// ---------------- per-node block-diagonal transform, v3 ----------------
// thread = (1 node, 1 head), owns all 32 outputs of its head. ~70 VGPRs, no spill.
// TR=1 (qt): out[n,r,h,i] = sum_j X[n,h*32+j] * Wg[r,h,i,j]
// TR=0 (mtp): out[n,r,h,j] = sum_i X[n,h*32+i] * Wg[r,h,i,j]
template<int TR>
__global__ __launch_bounds__(256, 2)
void k_blockdiag3(const u16* __restrict__ X, const float* __restrict__ Wg,
                  u16* __restrict__ Y, int n)
{
  const int WS_C = 36;      // words per contraction index (16B-aligned, bank-spread)
  const int WS_H = 1160;    // words per head (h steps banks by 8)
  __shared__ float Ws[T_H * WS_H];
  int r = blockIdx.y;
  int tid = threadIdx.x;
  // stage W into LDS, layout Ws[h][c][o] (c = contraction index)
#pragma unroll
  for (int k = 0; k < 16; ++k){
    int idx = tid + k*256;
    int a = idx & 31;            // contiguous (last) index j of Wg[r][h][i][j]
    int b = (idx >> 5) & 31;     // index i
    int h = idx >> 10;
    float wv = Wg[(((size_t)r*T_H + h)*T_DK + b)*T_DK + a];
    if (TR) Ws[h*WS_H + a*WS_C + b] = wv;   // c=j, o=i
    else    Ws[h*WS_H + b*WS_C + a] = wv;   // c=i, o=j
  }
  int h = tid & 3, p = tid >> 2;
  int node = (int)blockIdx.x * 64 + p;
  uint4 xq[4];
  if (node < n){
#pragma unroll
    for (int k = 0; k < 4; ++k)
      xq[k] = *(const uint4*)&X[(size_t)node*T_HD + h*T_DK + k*8];
  } else {
#pragma unroll
    for (int k = 0; k < 4; ++k) xq[k] = make_uint4(0,0,0,0);
  }
  __syncthreads();
  float4 acc[8];
#pragma unroll
  for (int og=0;og<8;og++) acc[og] = make_float4(0.f,0.f,0.f,0.f);
  const float* Wh = &Ws[h*WS_H];
#pragma unroll
  for (int c = 0; c < 32; ++c){
    unsigned int w = ((const unsigned int*)xq)[c>>1];
    float xv = (c&1) ? __uint_as_float(w & 0xffff0000u) : __uint_as_float(w << 16);
#pragma unroll
    for (int og = 0; og < 8; ++og){
      float4 w4 = *(const float4*)&Wh[c*WS_C + og*4];
      acc[og].x += xv*w4.x;
      acc[og].y += xv*w4.y;
      acc[og].z += xv*w4.z;
      acc[og].w += xv*w4.w;
    }
  }
  if (node < n){
    u16* yb = &Y[(size_t)node*(T_R*T_HD) + (size_t)r*T_HD + h*T_DK];
#pragma unroll
    for (int og=0; og<8; og+=2){
      uint4 o4;
      o4.x = (unsigned int)f2bf(acc[og].x)   | ((unsigned int)f2bf(acc[og].y)   << 16);
      o4.y = (unsigned int)f2bf(acc[og].z)   | ((unsigned int)f2bf(acc[og].w)   << 16);
      o4.z = (unsigned int)f2bf(acc[og+1].x) | ((unsigned int)f2bf(acc[og+1].y) << 16);
      o4.w = (unsigned int)f2bf(acc[og+1].z) | ((unsigned int)f2bf(acc[og+1].w) << 16);
      *(uint4*)&yb[og*4] = o4;
    }
  }
}

// ---------------- per-dst edge attention (one wave per dst, online softmax) ----------------
__global__ __launch_bounds__(256)
void k_edge_attn(const u16* __restrict__ kB, const u16* __restrict__ qt,
                 const u16* __restrict__ mtp, const int* __restrict__ rp,
                 const int* __restrict__ packed, const float* __restrict__ pri,
                 float* __restrict__ resb, int n)
{
  int lane = threadIdx.x & 63;
  int wid = (int)blockIdx.x * (blockDim.x >> 6) + (threadIdx.x >> 6);
  int nw = (int)gridDim.x * (blockDim.x >> 6);
  int h1 = lane >> 5;           // head of first half: 0/1; second half head = h1+2
  const float isd = 0.17677669529663687f;
  float pr1[T_R], pr2[T_R];
#pragma unroll
  for (int r=0;r<T_R;r++){
    pr1[r] = pri[r*T_H + h1] * isd;
    pr2[r] = pri[r*T_H + h1 + 2] * isd;
  }
  for (int dst = wid; dst < n; dst += nw){
    int e0 = rp[dst], e1 = rp[dst+1];
    size_t qbase = (size_t)dst * (T_R*T_HD);
    float u1[T_R], u2[T_R];
#pragma unroll
    for (int r=0;r<T_R;r++){
      u1[r] = bf2f(qt[qbase + r*T_HD + lane]);
      u2[r] = bf2f(qt[qbase + r*T_HD + 64 + lane]);
    }
    float m1=-INFINITY, m2=-INFINITY, d1=0.f, d2=0.f, a1=0.f, a2=0.f;
    for (int ei=e0; ei<e1; ++ei){
      int pk = packed[ei];
      int s = pk & 131071;
      int rt = pk >> 17;
      float ka = bf2f(kB[(size_t)s*T_HD + lane]);
      float kb = bf2f(kB[(size_t)s*T_HD + 64 + lane]);
      float ua, ub, pa, pb;
      switch(rt){
        case 0: ua=u1[0]; ub=u2[0]; pa=pr1[0]; pb=pr2[0]; break;
        case 1: ua=u1[1]; ub=u2[1]; pa=pr1[1]; pb=pr2[1]; break;
        case 2: ua=u1[2]; ub=u2[2]; pa=pr1[2]; pb=pr2[2]; break;
        case 3: ua=u1[3]; ub=u2[3]; pa=pr1[3]; pb=pr2[3]; break;
        default:ua=u1[4]; ub=u2[4]; pa=pr1[4]; pb=pr2[4]; break;
      }
      float p1 = ua*ka, p2 = ub*kb;
#pragma unroll
      for (int o=16;o>=1;o>>=1){
        p1 += __shfl_xor(p1, o, 32);
        p2 += __shfl_xor(p2, o, 32);
      }
      float s1 = p1*pa, s2 = p2*pb;
      size_t mb = (size_t)s*(T_R*T_HD) + (size_t)rt*T_HD;
      float ma = bf2f(mtp[mb + lane]);
      float mv = bf2f(mtp[mb + 64 + lane]);
      float mn1 = fmaxf(m1, s1), mn2 = fmaxf(m2, s2);
      float sc1 = __expf(m1 - mn1), sc2 = __expf(m2 - mn2);
      float w1 = __expf(s1 - mn1), w2 = __expf(s2 - mn2);
      m1 = mn1; m2 = mn2;
      d1 = d1*sc1 + w1; d2 = d2*sc2 + w2;
      a1 = a1*sc1 + w1*ma; a2 = a2*sc2 + w2*mv;
    }
    float i1 = 1.f / fmaxf(d1, 1e-9f);
    float i2 = 1.f / fmaxf(d2, 1e-9f);
    resb[(size_t)dst*T_HD + lane]      = a1 * i1;
    resb[(size_t)dst*T_HD + 64 + lane] = a2 * i2;
  }
}

extern "C" void kernel_launch(void* const* d_in, const int* in_sizes, int n_in,
                              void* d_out, int out_size, void* d_ws, size_t ws_size,
                              hipStream_t stream)
{
  const float* node_feature = (const float*)d_in[0];
  const int* node_type    = (const int*)d_in[1];
  // d_in[2] edge_time: unused by the reference
  const int* edge_index   = (const int*)d_in[3];
  const int* edge_type    = (const int*)d_in[4];
  const float* adapt_w = (const float*)d_in[5];
  const float* adapt_b = (const float*)d_in[6];
  const float* kw = (const float*)d_in[7];
  const float* kb = (const float*)d_in[8];
  const float* qw = (const float*)d_in[9];
  const float* qb = (const float*)d_in[10];
  const float* vw = (const float*)d_in[11];
  const float* vb = (const float*)d_in[12];
  const float* aw = (const float*)d_in[13];
  const float* ab = (const float*)d_in[14];
  const float* rel_pri = (const float*)d_in[15];
  const float* rel_att = (const float*)d_in[16];
  const float* rel_msg = (const float*)d_in[17];
  const float* skipp   = (const float*)d_in[18];

  const int N = in_sizes[1];
  const int E = in_sizes[4];
  const int* srcp = edge_index;
  const int* dstp = edge_index + E;

  char* p = (char*)d_ws;
  auto take = [&](size_t bytes)->char*{
    char* r = p; p += (bytes + 255) & ~(size_t)255; return r;
  };
  float* h0   = (float*)take((size_t)N*T_HD*4);      // 25.6 MB f32 features
  u16*  kB    = (u16*) take((size_t)N*T_HD*2);       // 12.8 MB
  u16*  qB    = (u16*) take((size_t)N*T_HD*2);       // 12.8 MB
  u16*  vB    = (u16*) take((size_t)N*T_HD*2);       // 12.8 MB (contiguous with qB)
  float* resb = (float*)qB;                          // alias qB+vB (dead once qt/mtp built)
  u16*  qt    = (u16*) take((size_t)N*T_R*T_HD*2);   // 64 MB
  u16*  mtp   = (u16*) take((size_t)N*T_R*T_HD*2);   // 64 MB
  int* degp   = (int*) take((size_t)N*16*4);         // 3.2 MB line-padded counters
  int* rp     = (int*) take(((size_t)N+1)*4);
  int* rank   = (int*) take((size_t)E*4);
  int* packed = (int*) take((size_t)E*4);
  int* tcnt   = (int*) take(256);
  int* toff   = (int*) take(256);
  int* tcur   = (int*) take(256);
  int* tperm  = (int*) take((size_t)N*4);

  hipMemsetAsync(degp, 0, (size_t)N*16*4, stream);
  hipMemsetAsync(tcnt, 0, 256, stream);

  int nb_n4 = (N + 1023)/1024, nb_e = (E + 255)/256;
  k_hist4<<<nb_n4, 256, 0, stream>>>(node_type, tcnt, N);
  k_deg<<<nb_e, 256, 0, stream>>>(dstp, degp, rank, E);
  k_toff<<<1, 64, 0, stream>>>(tcnt, toff, tcur);
  k_scan2<<<1, 1024, 0, stream>>>(degp, rp, N);
  k_scatter2<<<nb_n4, 256, 0, stream>>>(node_type, tcur, tperm, N);
  k_fill2<<<nb_e, 256, 0, stream>>>(srcp, dstp, edge_type, rp, rank, packed, E);

  dim3 gg((N + 63)/64, T_NT);
  dim3 gb3((N + 63)/64, T_R);
  // adapt: h0 = tanh(node_feature @ adapt_w[t] + adapt_b[t])
  k_typed_gemm<1,0><<<gg, 256, 0, stream>>>(node_feature, tperm, toff, adapt_w, adapt_b, h0, nullptr, nullptr);

  for (int l = 0; l < T_L; ++l){
    size_t wo = (size_t)l * T_NT * T_HD * T_HD;
    size_t bo = (size_t)l * T_NT * T_HD;
    size_t ro = (size_t)l * T_R * T_H * T_DK * T_DK;
    k_typed_gemm<0,1><<<gg, 256, 0, stream>>>(h0, tperm, toff, kw+wo, kb+bo, kB, nullptr, nullptr);
    k_typed_gemm<0,1><<<gg, 256, 0, stream>>>(h0, tperm, toff, qw+wo, qb+bo, qB, nullptr, nullptr);
    k_typed_gemm<0,1><<<gg, 256, 0, stream>>>(h0, tperm, toff, vw+wo, vb+bo, vB, nullptr, nullptr);
    k_blockdiag3<1><<<gb3, 256, 0, stream>>>(qB, rel_att + ro, qt, N);   // qt[n,r,h,i] = sum_j A[r,h,i,j] q[n,h,j]
    k_blockdiag3<0><<<gb3, 256, 0, stream>>>(vB, rel_msg + ro, mtp, N);  // mtp[n,r,h,j] = sum_i v[n,h,i] M[r,h,i,j]
    k_edge_attn<<<2048, 256, 0, stream>>>(kB, qt, mtp, rp, packed, rel_pri + (size_t)l*T_R*T_H, resb, N);
    if (l == T_L - 1)
      k_typed_gemm<3,0><<<gg, 256, 0, stream>>>(resb, tperm, toff, aw+wo, ab+bo, d_out, h0, skipp + l*T_NT);
    else
      k_typed_gemm<3,0><<<gg, 256, 0, stream>>>(resb, tperm, toff, aw+wo, ab+bo, h0, h0, skipp + l*T_NT);
  }
}

// Round 6
// 835.992 us; speedup vs baseline: 10.4400x; 1.1160x over previous
//
#include <hip/hip_runtime.h>

#define T_NT 4
#define T_R  5
#define T_H  4
#define T_DK 32
#define T_HD 128
#define T_L  2

typedef unsigned short u16;

__device__ __forceinline__ float bf2f(u16 u){
  union { float f; unsigned int i; } v; v.i = ((unsigned int)u) << 16; return v.f;
}
__device__ __forceinline__ u16 f2bf(float f){
  union { float f; unsigned int i; } v; v.f = f;
  unsigned int x = v.i;
  return (u16)((x + 0x7fffu + ((x >> 16) & 1u)) >> 16);
}
__device__ __forceinline__ float gelu_f(float x){
  float x3 = x*x*x;
  return 0.5f * x * (1.f + tanhf(0.7978845608028654f * (x + 0.044715f * x3)));
}

// ---------------- CSR / bucket build (LDS-aggregated, line-padded) ----------------
__global__ void k_hist4(const int* __restrict__ key, int* __restrict__ cnt, int n){
  __shared__ int c[T_NT];
  int tid = threadIdx.x;
  if (tid < T_NT) c[tid] = 0;
  __syncthreads();
  int base = blockIdx.x*1024;
#pragma unroll
  for (int j=0;j<4;j++){
    int i = base + tid + j*256;
    if (i < n) atomicAdd(&c[key[i]], 1);
  }
  __syncthreads();
  if (tid < T_NT) atomicAdd(&cnt[tid], c[tid]);
}

__global__ void k_toff(const int* __restrict__ cnt, int* __restrict__ off, int* __restrict__ tcur){
  if (threadIdx.x == 0){
    off[0] = 0;
    for (int t = 0; t < T_NT; ++t) off[t+1] = off[t] + cnt[t];
    for (int t = 0; t < T_NT; ++t) tcur[t] = off[t];
  }
}

__global__ void k_scatter2(const int* __restrict__ nt, int* __restrict__ tcur,
                           int* __restrict__ perm, int n){
  __shared__ int lc[T_NT], lb[T_NT];
  int tid = threadIdx.x;
  if (tid < T_NT) lc[tid] = 0;
  __syncthreads();
  int base = blockIdx.x*1024;
  int t[4], lr[4];
#pragma unroll
  for (int j=0;j<4;j++){
    int i = base + tid + j*256;
    if (i < n){ t[j] = nt[i]; lr[j] = atomicAdd(&lc[t[j]], 1); }
    else t[j] = -1;
  }
  __syncthreads();
  if (tid < T_NT) lb[tid] = atomicAdd(&tcur[tid], lc[tid]);
  __syncthreads();
#pragma unroll
  for (int j=0;j<4;j++){
    if (t[j] >= 0) perm[lb[t[j]] + lr[j]] = base + tid + j*256;
  }
}

// degree histogram with 64B-padded counters; captures per-edge rank
__global__ void k_deg(const int* __restrict__ dstp, int* __restrict__ degp,
                      int* __restrict__ rank, int n){
  int i = blockIdx.x*256 + threadIdx.x;
  if (i < n) rank[i] = atomicAdd(&degp[(size_t)dstp[i] << 4], 1);
}

// ---------------- multi-block scan (3 tiny kernels) ----------------
__global__ void k_scanA(const int* __restrict__ degp, int* __restrict__ rp,
                        int* __restrict__ bsum, int n){
  __shared__ int buf[256];
  int tid = threadIdx.x;
  int i = blockIdx.x*256 + tid;
  int v = (i < n) ? degp[(size_t)i << 4] : 0;
  buf[tid] = v;
  __syncthreads();
  for (int off = 1; off < 256; off <<= 1){
    int add = (tid >= off) ? buf[tid - off] : 0;
    __syncthreads();
    buf[tid] += add;
    __syncthreads();
  }
  if (i < n) rp[i] = buf[tid] - v;          // local exclusive prefix
  if (tid == 255) bsum[blockIdx.x] = buf[255];
}
__global__ void k_scanB(int* __restrict__ bsum, int nb){
  __shared__ int buf[1024];
  int tid = threadIdx.x;
  int v = (tid < nb) ? bsum[tid] : 0;
  buf[tid] = v;
  __syncthreads();
  for (int off = 1; off < 1024; off <<= 1){
    int add = (tid >= off) ? buf[tid - off] : 0;
    __syncthreads();
    buf[tid] += add;
    __syncthreads();
  }
  if (tid < nb) bsum[tid] = buf[tid] - v;   // exclusive block offsets
}
__global__ void k_scanC(int* __restrict__ rp, const int* __restrict__ bsum,
                        int n, int E){
  int i = blockIdx.x*256 + threadIdx.x;
  if (i < n) rp[i] += bsum[blockIdx.x];
  if (i == 0) rp[n] = E;
}

// atomic-free edge placement using precomputed ranks
__global__ void k_fill2(const int* __restrict__ srcp, const int* __restrict__ dstp,
                        const int* __restrict__ etp, const int* __restrict__ rp,
                        const int* __restrict__ rank, int* __restrict__ packed, int n){
  int i = blockIdx.x*256 + threadIdx.x;
  if (i < n){
    int d = dstp[i];
    packed[rp[d] + rank[i]] = srcp[i] | (etp[i] << 17);   // N=50000 < 2^17
  }
}

// ---------------- per-type gathered GEMM (f32 in, f32 weights, fp32 accum) ----------------
// MODE: 0 plain, 1 tanh epilogue (adapt), 3 gelu-on-input + gated residual (update)
// OB: 1 -> out bf16 (u16), 0 -> out f32
template<int MODE, int OB>
__global__ __launch_bounds__(256)
void k_typed_gemm(const float* __restrict__ X,
                  const int* __restrict__ tperm, const int* __restrict__ toff,
                  const float* __restrict__ W, const float* __restrict__ Bi,
                  void* __restrict__ outv,
                  const float* __restrict__ h_in, const float* __restrict__ skipv)
{
  int t = blockIdx.y;
  int lo = toff[t], cnt = toff[t+1] - lo;
  int base = (int)blockIdx.x * 64;
  if (base >= cnt) return;
  __shared__ float As[64][16];
  __shared__ float Bs[16][128];
  __shared__ int rows_s[64];
  int tid = threadIdx.x;
  if (tid < 64){
    int m = base + tid;
    rows_s[tid] = (m < cnt) ? tperm[lo + m] : -1;
  }
  __syncthreads();
  float acc[8][4];
#pragma unroll
  for (int i=0;i<8;i++){ acc[i][0]=0.f;acc[i][1]=0.f;acc[i][2]=0.f;acc[i][3]=0.f; }
  int ty = tid >> 5, tx = tid & 31;
  const float* Wt = W + (size_t)t * (T_HD*T_HD);
  for (int k0 = 0; k0 < T_HD; k0 += 16){
#pragma unroll
    for (int j=0;j<4;j++){
      int idx = tid + j*256;
      int m = idx >> 4, kk = idx & 15;
      int row = rows_s[m];
      float v = 0.f;
      if (row >= 0){
        v = X[(size_t)row*T_HD + k0 + kk];
        if (MODE == 3) v = gelu_f(v);
      }
      As[m][kk] = v;
    }
#pragma unroll
    for (int j=0;j<8;j++){
      int idx = tid + j*256;
      int kk = idx >> 7, c = idx & 127;
      Bs[kk][c] = Wt[(size_t)(k0+kk)*T_HD + c];
    }
    __syncthreads();
#pragma unroll
    for (int kk=0;kk<16;kk++){
      float4 bv = *(const float4*)&Bs[kk][tx*4];
#pragma unroll
      for (int i=0;i<8;i++){
        float a = As[ty*8+i][kk];
        acc[i][0] += a*bv.x; acc[i][1] += a*bv.y; acc[i][2] += a*bv.z; acc[i][3] += a*bv.w;
      }
    }
    __syncthreads();
  }
  float sk = 0.f;
  if (MODE == 3) sk = 1.f / (1.f + __expf(-skipv[t]));
#pragma unroll
  for (int i=0;i<8;i++){
    int m = ty*8 + i;
    int row = rows_s[m];
    if (row < 0) continue;
#pragma unroll
    for (int q=0;q<4;q++){
      int c = tx*4 + q;
      float vv = acc[i][q] + Bi[t*T_HD + c];
      if (MODE == 1) vv = tanhf(vv);
      if (MODE == 3) vv = vv*sk + h_in[(size_t)row*T_HD + c]*(1.f - sk);
      if (OB) ((u16*)outv)[(size_t)row*T_HD + c] = f2bf(vv);
      else    ((float*)outv)[(size_t)row*T_HD + c] = vv;
    }
  }
}

// ---------------- per-node block-diagonal transform, v3 ----------------
// thread = (1 node, 1 head), owns all 32 outputs of its head. ~70 VGPRs, no spill.
// TR=1 (qt): out[n,r,h,i] = sum_j X[n,h*32+j] * Wg[r,h,i,j]
// TR=0 (mtp): out[n,r,h,j] = sum_i X[n,h*32+i] * Wg[r,h,i,j]
template<int TR>
__global__ __launch_bounds__(256, 2)
void k_blockdiag3(const u16* __restrict__ X, const float* __restrict__ Wg,
                  u16* __restrict__ Y, int n)
{
  const int WS_C = 36;      // words per contraction index (16B-aligned, bank-spread)
  const int WS_H = 1160;    // words per head (h steps banks by 8)
  __shared__ float Ws[T_H * WS_H];
  int r = blockIdx.y;
  int tid = threadIdx.x;
  // stage W into LDS, layout Ws[h][c][o] (c = contraction index)
#pragma unroll
  for (int k = 0; k < 16; ++k){
    int idx = tid + k*256;
    int a = idx & 31;            // contiguous (last) index j of Wg[r][h][i][j]
    int b = (idx >> 5) & 31;     // index i
    int h = idx >> 10;
    float wv = Wg[(((size_t)r*T_H + h)*T_DK + b)*T_DK + a];
    if (TR) Ws[h*WS_H + a*WS_C + b] = wv;   // c=j, o=i
    else    Ws[h*WS_H + b*WS_C + a] = wv;   // c=i, o=j
  }
  int h = tid & 3, p = tid >> 2;
  int node = (int)blockIdx.x * 64 + p;
  uint4 xq[4];
  if (node < n){
#pragma unroll
    for (int k = 0; k < 4; ++k)
      xq[k] = *(const uint4*)&X[(size_t)node*T_HD + h*T_DK + k*8];
  } else {
#pragma unroll
    for (int k = 0; k < 4; ++k) xq[k] = make_uint4(0,0,0,0);
  }
  __syncthreads();
  float4 acc[8];
#pragma unroll
  for (int og=0;og<8;og++) acc[og] = make_float4(0.f,0.f,0.f,0.f);
  const float* Wh = &Ws[h*WS_H];
#pragma unroll
  for (int c = 0; c < 32; ++c){
    unsigned int w = ((const unsigned int*)xq)[c>>1];
    float xv = (c&1) ? __uint_as_float(w & 0xffff0000u) : __uint_as_float(w << 16);
#pragma unroll
    for (int og = 0; og < 8; ++og){
      float4 w4 = *(const float4*)&Wh[c*WS_C + og*4];
      acc[og].x += xv*w4.x;
      acc[og].y += xv*w4.y;
      acc[og].z += xv*w4.z;
      acc[og].w += xv*w4.w;
    }
  }
  if (node < n){
    u16* yb = &Y[(size_t)node*(T_R*T_HD) + (size_t)r*T_HD + h*T_DK];
#pragma unroll
    for (int og=0; og<8; og+=2){
      uint4 o4;
      o4.x = (unsigned int)f2bf(acc[og].x)   | ((unsigned int)f2bf(acc[og].y)   << 16);
      o4.y = (unsigned int)f2bf(acc[og].z)   | ((unsigned int)f2bf(acc[og].w)   << 16);
      o4.z = (unsigned int)f2bf(acc[og+1].x) | ((unsigned int)f2bf(acc[og+1].y) << 16);
      o4.w = (unsigned int)f2bf(acc[og+1].z) | ((unsigned int)f2bf(acc[og+1].w) << 16);
      *(uint4*)&yb[og*4] = o4;
    }
  }
}

// ---------------- per-dst edge attention (one wave per dst, online softmax) ----------------
__global__ __launch_bounds__(256)
void k_edge_attn(const u16* __restrict__ kB, const u16* __restrict__ qt,
                 const u16* __restrict__ mtp, const int* __restrict__ rp,
                 const int* __restrict__ packed, const float* __restrict__ pri,
                 float* __restrict__ resb, int n)
{
  int lane = threadIdx.x & 63;
  int wid = (int)blockIdx.x * (blockDim.x >> 6) + (threadIdx.x >> 6);
  int nw = (int)gridDim.x * (blockDim.x >> 6);
  int h1 = lane >> 5;           // head of first half: 0/1; second half head = h1+2
  const float isd = 0.17677669529663687f;
  float pr1[T_R], pr2[T_R];
#pragma unroll
  for (int r=0;r<T_R;r++){
    pr1[r] = pri[r*T_H + h1] * isd;
    pr2[r] = pri[r*T_H + h1 + 2] * isd;
  }
  for (int dst = wid; dst < n; dst += nw){
    int e0 = rp[dst], e1 = rp[dst+1];
    size_t qbase = (size_t)dst * (T_R*T_HD);
    float u1[T_R], u2[T_R];
#pragma unroll
    for (int r=0;r<T_R;r++){
      u1[r] = bf2f(qt[qbase + r*T_HD + lane]);
      u2[r] = bf2f(qt[qbase + r*T_HD + 64 + lane]);
    }
    float m1=-INFINITY, m2=-INFINITY, d1=0.f, d2=0.f, a1=0.f, a2=0.f;
    for (int ei=e0; ei<e1; ++ei){
      int pk = packed[ei];
      int s = pk & 131071;
      int rt = pk >> 17;
      float ka = bf2f(kB[(size_t)s*T_HD + lane]);
      float kb = bf2f(kB[(size_t)s*T_HD + 64 + lane]);
      float ua, ub, pa, pb;
      switch(rt){
        case 0: ua=u1[0]; ub=u2[0]; pa=pr1[0]; pb=pr2[0]; break;
        case 1: ua=u1[1]; ub=u2[1]; pa=pr1[1]; pb=pr2[1]; break;
        case 2: ua=u1[2]; ub=u2[2]; pa=pr1[2]; pb=pr2[2]; break;
        case 3: ua=u1[3]; ub=u2[3]; pa=pr1[3]; pb=pr2[3]; break;
        default:ua=u1[4]; ub=u2[4]; pa=pr1[4]; pb=pr2[4]; break;
      }
      float p1 = ua*ka, p2 = ub*kb;
#pragma unroll
      for (int o=16;o>=1;o>>=1){
        p1 += __shfl_xor(p1, o, 32);
        p2 += __shfl_xor(p2, o, 32);
      }
      float s1 = p1*pa, s2 = p2*pb;
      size_t mb = (size_t)s*(T_R*T_HD) + (size_t)rt*T_HD;
      float ma = bf2f(mtp[mb + lane]);
      float mv = bf2f(mtp[mb + 64 + lane]);
      float mn1 = fmaxf(m1, s1), mn2 = fmaxf(m2, s2);
      float sc1 = __expf(m1 - mn1), sc2 = __expf(m2 - mn2);
      float w1 = __expf(s1 - mn1), w2 = __expf(s2 - mn2);
      m1 = mn1; m2 = mn2;
      d1 = d1*sc1 + w1; d2 = d2*sc2 + w2;
      a1 = a1*sc1 + w1*ma; a2 = a2*sc2 + w2*mv;
    }
    float i1 = 1.f / fmaxf(d1, 1e-9f);
    float i2 = 1.f / fmaxf(d2, 1e-9f);
    resb[(size_t)dst*T_HD + lane]      = a1 * i1;
    resb[(size_t)dst*T_HD + 64 + lane] = a2 * i2;
  }
}

extern "C" void kernel_launch(void* const* d_in, const int* in_sizes, int n_in,
                              void* d_out, int out_size, void* d_ws, size_t ws_size,
                              hipStream_t stream)
{
  const float* node_feature = (const float*)d_in[0];
  const int* node_type    = (const int*)d_in[1];
  // d_in[2] edge_time: unused by the reference
  const int* edge_index   = (const int*)d_in[3];
  const int* edge_type    = (const int*)d_in[4];
  const float* adapt_w = (const float*)d_in[5];
  const float* adapt_b = (const float*)d_in[6];
  const float* kw = (const float*)d_in[7];
  const float* kb = (const float*)d_in[8];
  const float* qw = (const float*)d_in[9];
  const float* qb = (const float*)d_in[10];
  const float* vw = (const float*)d_in[11];
  const float* vb = (const float*)d_in[12];
  const float* aw = (const float*)d_in[13];
  const float* ab = (const float*)d_in[14];
  const float* rel_pri = (const float*)d_in[15];
  const float* rel_att = (const float*)d_in[16];
  const float* rel_msg = (const float*)d_in[17];
  const float* skipp   = (const float*)d_in[18];

  const int N = in_sizes[1];
  const int E = in_sizes[4];
  const int* srcp = edge_index;
  const int* dstp = edge_index + E;

  char* p = (char*)d_ws;
  auto take = [&](size_t bytes)->char*{
    char* r = p; p += (bytes + 255) & ~(size_t)255; return r;
  };
  float* h0   = (float*)take((size_t)N*T_HD*4);      // 25.6 MB f32 features
  u16*  kB    = (u16*) take((size_t)N*T_HD*2);       // 12.8 MB
  u16*  qB    = (u16*) take((size_t)N*T_HD*2);       // 12.8 MB
  u16*  vB    = (u16*) take((size_t)N*T_HD*2);       // 12.8 MB (contiguous with qB)
  float* resb = (float*)qB;                          // alias qB+vB (dead once qt/mtp built)
  u16*  qt    = (u16*) take((size_t)N*T_R*T_HD*2);   // 64 MB
  u16*  mtp   = (u16*) take((size_t)N*T_R*T_HD*2);   // 64 MB
  int* degp   = (int*) take((size_t)N*16*4);         // 3.2 MB line-padded counters
  int* rp     = (int*) take(((size_t)N+1)*4);
  int* rank   = (int*) take((size_t)E*4);
  int* packed = (int*) take((size_t)E*4);
  int* tcnt   = (int*) take(256);
  int* toff   = (int*) take(256);
  int* tcur   = (int*) take(256);
  int* bsum   = (int*) take(1024);
  int* tperm  = (int*) take((size_t)N*4);

  hipMemsetAsync(degp, 0, (size_t)N*16*4, stream);
  hipMemsetAsync(tcnt, 0, 256, stream);

  int nb_n4 = (N + 1023)/1024, nb_e = (E + 255)/256;
  int nb_s  = (N + 255)/256;
  k_hist4<<<nb_n4, 256, 0, stream>>>(node_type, tcnt, N);
  k_deg<<<nb_e, 256, 0, stream>>>(dstp, degp, rank, E);
  k_toff<<<1, 64, 0, stream>>>(tcnt, toff, tcur);
  k_scanA<<<nb_s, 256, 0, stream>>>(degp, rp, bsum, N);
  k_scanB<<<1, 1024, 0, stream>>>(bsum, nb_s);
  k_scanC<<<nb_s, 256, 0, stream>>>(rp, bsum, N, E);
  k_scatter2<<<nb_n4, 256, 0, stream>>>(node_type, tcur, tperm, N);
  k_fill2<<<nb_e, 256, 0, stream>>>(srcp, dstp, edge_type, rp, rank, packed, E);

  dim3 gg((N + 63)/64, T_NT);
  dim3 gb3((N + 63)/64, T_R);
  // adapt: h0 = tanh(node_feature @ adapt_w[t] + adapt_b[t])
  k_typed_gemm<1,0><<<gg, 256, 0, stream>>>(node_feature, tperm, toff, adapt_w, adapt_b, h0, nullptr, nullptr);

  for (int l = 0; l < T_L; ++l){
    size_t wo = (size_t)l * T_NT * T_HD * T_HD;
    size_t bo = (size_t)l * T_NT * T_HD;
    size_t ro = (size_t)l * T_R * T_H * T_DK * T_DK;
    k_typed_gemm<0,1><<<gg, 256, 0, stream>>>(h0, tperm, toff, kw+wo, kb+bo, kB, nullptr, nullptr);
    k_typed_gemm<0,1><<<gg, 256, 0, stream>>>(h0, tperm, toff, qw+wo, qb+bo, qB, nullptr, nullptr);
    k_typed_gemm<0,1><<<gg, 256, 0, stream>>>(h0, tperm, toff, vw+wo, vb+bo, vB, nullptr, nullptr);
    k_blockdiag3<1><<<gb3, 256, 0, stream>>>(qB, rel_att + ro, qt, N);   // qt[n,r,h,i] = sum_j A[r,h,i,j] q[n,h,j]
    k_blockdiag3<0><<<gb3, 256, 0, stream>>>(vB, rel_msg + ro, mtp, N);  // mtp[n,r,h,j] = sum_i v[n,h,i] M[r,h,i,j]
    k_edge_attn<<<2048, 256, 0, stream>>>(kB, qt, mtp, rp, packed, rel_pri + (size_t)l*T_R*T_H, resb, N);
    if (l == T_L - 1)
      k_typed_gemm<3,0><<<gg, 256, 0, stream>>>(resb, tperm, toff, aw+wo, ab+bo, d_out, h0, skipp + l*T_NT);
    else
      k_typed_gemm<3,0><<<gg, 256, 0, stream>>>(resb, tperm, toff, aw+wo, ab+bo, h0, h0, skipp + l*T_NT);
  }
}

// Round 7
// 634.774 us; speedup vs baseline: 13.7495x; 1.3170x over previous
//
#include <hip/hip_runtime.h>

#define T_NT 4
#define T_R  5
#define T_H  4
#define T_DK 32
#define T_HD 128
#define T_L  2
#define NCOL 1408   // 128 (k) + 640 (qt) + 640 (mtp)

typedef unsigned short u16;
typedef __bf16 bf8_t __attribute__((ext_vector_type(8)));
typedef float f4_t __attribute__((ext_vector_type(4)));

__device__ __forceinline__ float bf2f(u16 u){
  union { float f; unsigned int i; } v; v.i = ((unsigned int)u) << 16; return v.f;
}
__device__ __forceinline__ u16 f2bf(float f){
  union { float f; unsigned int i; } v; v.f = f;
  unsigned int x = v.i;
  return (u16)((x + 0x7fffu + ((x >> 16) & 1u)) >> 16);
}
__device__ __forceinline__ float gelu_f(float x){
  float x3 = x*x*x;
  return 0.5f * x * (1.f + tanhf(0.7978845608028654f * (x + 0.044715f * x3)));
}

// ---------------- CSR / bucket build ----------------
__global__ void k_hist4(const int* __restrict__ key, int* __restrict__ cnt, int n){
  __shared__ int c[T_NT];
  int tid = threadIdx.x;
  if (tid < T_NT) c[tid] = 0;
  __syncthreads();
  int base = blockIdx.x*1024;
#pragma unroll
  for (int j=0;j<4;j++){
    int i = base + tid + j*256;
    if (i < n) atomicAdd(&c[key[i]], 1);
  }
  __syncthreads();
  if (tid < T_NT) atomicAdd(&cnt[tid], c[tid]);
}

__global__ void k_toff(const int* __restrict__ cnt, int* __restrict__ off, int* __restrict__ tcur){
  if (threadIdx.x == 0){
    off[0] = 0;
    for (int t = 0; t < T_NT; ++t) off[t+1] = off[t] + cnt[t];
    for (int t = 0; t < T_NT; ++t) tcur[t] = off[t];
  }
}

__global__ void k_scatter2(const int* __restrict__ nt, int* __restrict__ tcur,
                           int* __restrict__ perm, int n){
  __shared__ int lc[T_NT], lb[T_NT];
  int tid = threadIdx.x;
  if (tid < T_NT) lc[tid] = 0;
  __syncthreads();
  int base = blockIdx.x*1024;
  int t[4], lr[4];
#pragma unroll
  for (int j=0;j<4;j++){
    int i = base + tid + j*256;
    if (i < n){ t[j] = nt[i]; lr[j] = atomicAdd(&lc[t[j]], 1); }
    else t[j] = -1;
  }
  __syncthreads();
  if (tid < T_NT) lb[tid] = atomicAdd(&tcur[tid], lc[tid]);
  __syncthreads();
#pragma unroll
  for (int j=0;j<4;j++){
    if (t[j] >= 0) perm[lb[t[j]] + lr[j]] = base + tid + j*256;
  }
}

__global__ void k_deg(const int* __restrict__ dstp, int* __restrict__ degp,
                      int* __restrict__ rank, int n){
  int i = blockIdx.x*256 + threadIdx.x;
  if (i < n) rank[i] = atomicAdd(&degp[(size_t)dstp[i] << 4], 1);
}

__global__ void k_scanA(const int* __restrict__ degp, int* __restrict__ rp,
                        int* __restrict__ bsum, int n){
  __shared__ int buf[256];
  int tid = threadIdx.x;
  int i = blockIdx.x*256 + tid;
  int v = (i < n) ? degp[(size_t)i << 4] : 0;
  buf[tid] = v;
  __syncthreads();
  for (int off = 1; off < 256; off <<= 1){
    int add = (tid >= off) ? buf[tid - off] : 0;
    __syncthreads();
    buf[tid] += add;
    __syncthreads();
  }
  if (i < n) rp[i] = buf[tid] - v;
  if (tid == 255) bsum[blockIdx.x] = buf[255];
}
__global__ void k_scanB(int* __restrict__ bsum, int nb){
  __shared__ int buf[1024];
  int tid = threadIdx.x;
  int v = (tid < nb) ? bsum[tid] : 0;
  buf[tid] = v;
  __syncthreads();
  for (int off = 1; off < 1024; off <<= 1){
    int add = (tid >= off) ? buf[tid - off] : 0;
    __syncthreads();
    buf[tid] += add;
    __syncthreads();
  }
  if (tid < nb) bsum[tid] = buf[tid] - v;
}
__global__ void k_scanC(int* __restrict__ rp, const int* __restrict__ bsum,
                        int n, int E){
  int i = blockIdx.x*256 + threadIdx.x;
  if (i < n) rp[i] += bsum[blockIdx.x];
  if (i == 0) rp[n] = E;
}

__global__ void k_fill2(const int* __restrict__ srcp, const int* __restrict__ dstp,
                        const int* __restrict__ etp, const int* __restrict__ rp,
                        const int* __restrict__ rank, int* __restrict__ packed, int n){
  int i = blockIdx.x*256 + threadIdx.x;
  if (i < n){
    int d = dstp[i];
    packed[rp[d] + rank[i]] = srcp[i] | (etp[i] << 17);
  }
}

// ---------------- combined-weight prep ----------------
// Ball[l][t][col][k] (bf16, transposed for B-frag reads), biasall[l][t][col]
// col 0..127: k-proj; 128..767: qt (r,h,i); 768..1407: mtp (r,h,j)
__global__ void k_prepw(const float* __restrict__ kw, const float* __restrict__ qw,
                        const float* __restrict__ vw, const float* __restrict__ kb,
                        const float* __restrict__ qb, const float* __restrict__ vb,
                        const float* __restrict__ rel_att, const float* __restrict__ rel_msg,
                        u16* __restrict__ Ball, float* __restrict__ biasall)
{
  int idx = blockIdx.x*256 + threadIdx.x;   // 0 .. 1408*128-1
  int t = blockIdx.y, l = blockIdx.z;
  int col = idx >> 7, k = idx & 127;
  int lt = l*T_NT + t;
  const float* qwk = qw + ((size_t)lt*T_HD + k)*T_HD;
  const float* vwk = vw + ((size_t)lt*T_HD + k)*T_HD;
  float val, bias = 0.f;
  if (col < 128){
    val = kw[((size_t)lt*T_HD + k)*T_HD + col];
    if (k == 0) bias = kb[(size_t)lt*T_HD + col];
  } else if (col < 768){
    int cc = col - 128, r = cc >> 7, hd = cc & 127, h = hd >> 5, i = hd & 31;
    const float* Ar = rel_att + ((((size_t)l*T_R + r)*T_H + h)*T_DK + i)*T_DK;
    float s = 0.f, sb = 0.f;
    const float* qrow = qwk + h*T_DK;
    const float* qbr = qb + (size_t)lt*T_HD + h*T_DK;
#pragma unroll
    for (int j = 0; j < 32; ++j){
      s += qrow[j] * Ar[j];
      if (k == 0) sb += qbr[j] * Ar[j];
    }
    val = s; bias = sb;
  } else {
    int cc = col - 768, r = cc >> 7, hd = cc & 127, h = hd >> 5, j = hd & 31;
    const float* Mr = rel_msg + (((size_t)l*T_R + r)*T_H + h)*T_DK*T_DK + j;
    float s = 0.f, sb = 0.f;
    const float* vrow = vwk + h*T_DK;
    const float* vbr = vb + (size_t)lt*T_HD + h*T_DK;
#pragma unroll
    for (int i = 0; i < 32; ++i){
      float m = Mr[i*T_DK];
      s += vrow[i] * m;
      if (k == 0) sb += vbr[i] * m;
    }
    val = s; bias = sb;
  }
  Ball[((size_t)lt*NCOL + col)*T_HD + k] = f2bf(val);
  if (k == 0) biasall[(size_t)lt*NCOL + col] = bias;
}

// ---------------- fused per-type MFMA GEMM: h -> {kB, qt, mtp} ----------------
__global__ __launch_bounds__(256)
void k_qkvm(const float* __restrict__ X, const int* __restrict__ tperm,
            const int* __restrict__ toff, const u16* __restrict__ Ball,
            const float* __restrict__ biasall,
            u16* __restrict__ kB, u16* __restrict__ qt, u16* __restrict__ mtp)
{
  __shared__ u16 As[64*128];
  __shared__ int rows_s[64];
  int t = blockIdx.y;
  int lo = toff[t], cnt = toff[t+1] - lo;
  int base = (int)blockIdx.x * 64;
  if (base >= cnt) return;
  int tid = threadIdx.x;
  if (tid < 64) rows_s[tid] = (base + tid < cnt) ? tperm[lo + base + tid] : -1;
  __syncthreads();
  // stage A tile (f32 -> bf16), XOR-swizzled rows
#pragma unroll
  for (int it = 0; it < 4; ++it){
    int chunk = tid + it*256;            // 1024 chunks of 8 elems
    int row = chunk >> 4, c8 = (chunk & 15) << 3;
    int node = rows_s[row];
    uint4 o = make_uint4(0,0,0,0);
    if (node >= 0){
      const float* src = X + (size_t)node*T_HD + c8;
      float4 f0 = *(const float4*)src;
      float4 f1 = *(const float4*)(src + 4);
      o.x = (unsigned)f2bf(f0.x) | ((unsigned)f2bf(f0.y) << 16);
      o.y = (unsigned)f2bf(f0.z) | ((unsigned)f2bf(f0.w) << 16);
      o.z = (unsigned)f2bf(f1.x) | ((unsigned)f2bf(f1.y) << 16);
      o.w = (unsigned)f2bf(f1.z) | ((unsigned)f2bf(f1.w) << 16);
    }
    int off16 = (row*128 + c8) ^ ((row & 7) << 3);
    *(uint4*)&As[off16] = o;
  }
  __syncthreads();

  int wid = tid >> 6, lane = tid & 63;
  int lr = lane & 15, lg = lane >> 4;
  // a-frags: 4 row-strips x 4 k-steps, loaded once, reused for all col-chunks
  bf8_t a[4][4];
#pragma unroll
  for (int rs = 0; rs < 4; ++rs)
#pragma unroll
    for (int kk = 0; kk < 4; ++kk){
      int row = rs*16 + lr;
      int off16 = (row*128 + kk*32 + lg*8) ^ ((row & 7) << 3);
      a[rs][kk] = *(const bf8_t*)&As[off16];
    }
  int nod[4][4];
#pragma unroll
  for (int rs = 0; rs < 4; ++rs)
#pragma unroll
    for (int j = 0; j < 4; ++j)
      nod[rs][j] = rows_s[rs*16 + lg*4 + j];

  const u16* Bt = Ball + (size_t)t * NCOL * T_HD;
  const float* biast = biasall + (size_t)t * NCOL;

  for (int c = wid; c < NCOL/16; c += 4){
    int col = c*16 + lr;
    const u16* bp = Bt + (size_t)col*T_HD + lg*8;
    bf8_t b0 = *(const bf8_t*)(bp);
    bf8_t b1 = *(const bf8_t*)(bp + 32);
    bf8_t b2 = *(const bf8_t*)(bp + 64);
    bf8_t b3 = *(const bf8_t*)(bp + 96);
    f4_t acc[4];
#pragma unroll
    for (int rs = 0; rs < 4; ++rs) acc[rs] = (f4_t){0.f,0.f,0.f,0.f};
#pragma unroll
    for (int rs = 0; rs < 4; ++rs){
      acc[rs] = __builtin_amdgcn_mfma_f32_16x16x32_bf16(a[rs][0], b0, acc[rs], 0, 0, 0);
      acc[rs] = __builtin_amdgcn_mfma_f32_16x16x32_bf16(a[rs][1], b1, acc[rs], 0, 0, 0);
      acc[rs] = __builtin_amdgcn_mfma_f32_16x16x32_bf16(a[rs][2], b2, acc[rs], 0, 0, 0);
      acc[rs] = __builtin_amdgcn_mfma_f32_16x16x32_bf16(a[rs][3], b3, acc[rs], 0, 0, 0);
    }
    float bias = biast[col];
    u16* dst; int cofs, stride;
    if (c < 8)       { dst = kB;  cofs = col;        stride = T_HD; }
    else if (c < 48) { dst = qt;  cofs = col - 128;  stride = T_R*T_HD; }
    else             { dst = mtp; cofs = col - 768;  stride = T_R*T_HD; }
#pragma unroll
    for (int rs = 0; rs < 4; ++rs)
#pragma unroll
      for (int j = 0; j < 4; ++j){
        int node = nod[rs][j];
        if (node >= 0) dst[(size_t)node*stride + cofs] = f2bf(acc[rs][j] + bias);
      }
  }
}

// ---------------- per-type gathered GEMM (f32), adapt + update only ----------------
// MODE: 1 tanh epilogue (adapt), 3 gelu-on-input + gated residual (update)
template<int MODE>
__global__ __launch_bounds__(256)
void k_typed_gemm(const float* __restrict__ X,
                  const int* __restrict__ tperm, const int* __restrict__ toff,
                  const float* __restrict__ W, const float* __restrict__ Bi,
                  float* __restrict__ outv,
                  const float* __restrict__ h_in, const float* __restrict__ skipv)
{
  int t = blockIdx.y;
  int lo = toff[t], cnt = toff[t+1] - lo;
  int base = (int)blockIdx.x * 64;
  if (base >= cnt) return;
  __shared__ float As[64][16];
  __shared__ float Bs[16][128];
  __shared__ int rows_s[64];
  int tid = threadIdx.x;
  if (tid < 64){
    int m = base + tid;
    rows_s[tid] = (m < cnt) ? tperm[lo + m] : -1;
  }
  __syncthreads();
  float acc[8][4];
#pragma unroll
  for (int i=0;i<8;i++){ acc[i][0]=0.f;acc[i][1]=0.f;acc[i][2]=0.f;acc[i][3]=0.f; }
  int ty = tid >> 5, tx = tid & 31;
  const float* Wt = W + (size_t)t * (T_HD*T_HD);
  for (int k0 = 0; k0 < T_HD; k0 += 16){
#pragma unroll
    for (int j=0;j<4;j++){
      int idx = tid + j*256;
      int m = idx >> 4, kk = idx & 15;
      int row = rows_s[m];
      float v = 0.f;
      if (row >= 0){
        v = X[(size_t)row*T_HD + k0 + kk];
        if (MODE == 3) v = gelu_f(v);
      }
      As[m][kk] = v;
    }
#pragma unroll
    for (int j=0;j<8;j++){
      int idx = tid + j*256;
      int kk = idx >> 7, c = idx & 127;
      Bs[kk][c] = Wt[(size_t)(k0+kk)*T_HD + c];
    }
    __syncthreads();
#pragma unroll
    for (int kk=0;kk<16;kk++){
      float4 bv = *(const float4*)&Bs[kk][tx*4];
#pragma unroll
      for (int i=0;i<8;i++){
        float a = As[ty*8+i][kk];
        acc[i][0] += a*bv.x; acc[i][1] += a*bv.y; acc[i][2] += a*bv.z; acc[i][3] += a*bv.w;
      }
    }
    __syncthreads();
  }
  float sk = 0.f;
  if (MODE == 3) sk = 1.f / (1.f + __expf(-skipv[t]));
#pragma unroll
  for (int i=0;i<8;i++){
    int m = ty*8 + i;
    int row = rows_s[m];
    if (row < 0) continue;
#pragma unroll
    for (int q=0;q<4;q++){
      int c = tx*4 + q;
      float vv = acc[i][q] + Bi[t*T_HD + c];
      if (MODE == 1) vv = tanhf(vv);
      if (MODE == 3) vv = vv*sk + h_in[(size_t)row*T_HD + c]*(1.f - sk);
      outv[(size_t)row*T_HD + c] = vv;
    }
  }
}

// ---------------- per-dst edge attention (one wave per dst, online softmax) ----------------
__global__ __launch_bounds__(256)
void k_edge_attn(const u16* __restrict__ kB, const u16* __restrict__ qt,
                 const u16* __restrict__ mtp, const int* __restrict__ rp,
                 const int* __restrict__ packed, const float* __restrict__ pri,
                 float* __restrict__ resb, int n)
{
  int lane = threadIdx.x & 63;
  int wid = (int)blockIdx.x * (blockDim.x >> 6) + (threadIdx.x >> 6);
  int nw = (int)gridDim.x * (blockDim.x >> 6);
  int h1 = lane >> 5;
  const float isd = 0.17677669529663687f;
  float pr1[T_R], pr2[T_R];
#pragma unroll
  for (int r=0;r<T_R;r++){
    pr1[r] = pri[r*T_H + h1] * isd;
    pr2[r] = pri[r*T_H + h1 + 2] * isd;
  }
  for (int dst = wid; dst < n; dst += nw){
    int e0 = rp[dst], e1 = rp[dst+1];
    size_t qbase = (size_t)dst * (T_R*T_HD);
    float u1[T_R], u2[T_R];
#pragma unroll
    for (int r=0;r<T_R;r++){
      u1[r] = bf2f(qt[qbase + r*T_HD + lane]);
      u2[r] = bf2f(qt[qbase + r*T_HD + 64 + lane]);
    }
    float m1=-INFINITY, m2=-INFINITY, d1=0.f, d2=0.f, a1=0.f, a2=0.f;
    for (int ei=e0; ei<e1; ++ei){
      int pk = packed[ei];
      int s = pk & 131071;
      int rt = pk >> 17;
      float ka = bf2f(kB[(size_t)s*T_HD + lane]);
      float kb = bf2f(kB[(size_t)s*T_HD + 64 + lane]);
      float ua, ub, pa, pb;
      switch(rt){
        case 0: ua=u1[0]; ub=u2[0]; pa=pr1[0]; pb=pr2[0]; break;
        case 1: ua=u1[1]; ub=u2[1]; pa=pr1[1]; pb=pr2[1]; break;
        case 2: ua=u1[2]; ub=u2[2]; pa=pr1[2]; pb=pr2[2]; break;
        case 3: ua=u1[3]; ub=u2[3]; pa=pr1[3]; pb=pr2[3]; break;
        default:ua=u1[4]; ub=u2[4]; pa=pr1[4]; pb=pr2[4]; break;
      }
      float p1 = ua*ka, p2 = ub*kb;
#pragma unroll
      for (int o=16;o>=1;o>>=1){
        p1 += __shfl_xor(p1, o, 32);
        p2 += __shfl_xor(p2, o, 32);
      }
      float s1 = p1*pa, s2 = p2*pb;
      size_t mb = (size_t)s*(T_R*T_HD) + (size_t)rt*T_HD;
      float ma = bf2f(mtp[mb + lane]);
      float mv = bf2f(mtp[mb + 64 + lane]);
      float mn1 = fmaxf(m1, s1), mn2 = fmaxf(m2, s2);
      float sc1 = __expf(m1 - mn1), sc2 = __expf(m2 - mn2);
      float w1 = __expf(s1 - mn1), w2 = __expf(s2 - mn2);
      m1 = mn1; m2 = mn2;
      d1 = d1*sc1 + w1; d2 = d2*sc2 + w2;
      a1 = a1*sc1 + w1*ma; a2 = a2*sc2 + w2*mv;
    }
    float i1 = 1.f / fmaxf(d1, 1e-9f);
    float i2 = 1.f / fmaxf(d2, 1e-9f);
    resb[(size_t)dst*T_HD + lane]      = a1 * i1;
    resb[(size_t)dst*T_HD + 64 + lane] = a2 * i2;
  }
}

extern "C" void kernel_launch(void* const* d_in, const int* in_sizes, int n_in,
                              void* d_out, int out_size, void* d_ws, size_t ws_size,
                              hipStream_t stream)
{
  const float* node_feature = (const float*)d_in[0];
  const int* node_type    = (const int*)d_in[1];
  const int* edge_index   = (const int*)d_in[3];
  const int* edge_type    = (const int*)d_in[4];
  const float* adapt_w = (const float*)d_in[5];
  const float* adapt_b = (const float*)d_in[6];
  const float* kw = (const float*)d_in[7];
  const float* kb = (const float*)d_in[8];
  const float* qw = (const float*)d_in[9];
  const float* qb = (const float*)d_in[10];
  const float* vw = (const float*)d_in[11];
  const float* vb = (const float*)d_in[12];
  const float* aw = (const float*)d_in[13];
  const float* ab = (const float*)d_in[14];
  const float* rel_pri = (const float*)d_in[15];
  const float* rel_att = (const float*)d_in[16];
  const float* rel_msg = (const float*)d_in[17];
  const float* skipp   = (const float*)d_in[18];

  const int N = in_sizes[1];
  const int E = in_sizes[4];
  const int* srcp = edge_index;
  const int* dstp = edge_index + E;

  char* p = (char*)d_ws;
  auto take = [&](size_t bytes)->char*{
    char* r = p; p += (bytes + 255) & ~(size_t)255; return r;
  };
  float* h0   = (float*)take((size_t)N*T_HD*4);          // 25.6 MB
  float* resb = (float*)take((size_t)N*T_HD*4);          // 25.6 MB
  u16*  kB    = (u16*) take((size_t)N*T_HD*2);           // 12.8 MB
  u16*  qt    = (u16*) take((size_t)N*T_R*T_HD*2);       // 64 MB
  u16*  mtp   = (u16*) take((size_t)N*T_R*T_HD*2);       // 64 MB
  u16*  Ball  = (u16*) take((size_t)T_L*T_NT*NCOL*T_HD*2);   // 2.9 MB
  float* biasall = (float*)take((size_t)T_L*T_NT*NCOL*4);    // 45 KB
  int* degp   = (int*) take((size_t)N*16*4);
  int* rp     = (int*) take(((size_t)N+1)*4);
  int* rank   = (int*) take((size_t)E*4);
  int* packed = (int*) take((size_t)E*4);
  int* tcnt   = (int*) take(256);
  int* toff   = (int*) take(256);
  int* tcur   = (int*) take(256);
  int* bsum   = (int*) take(1024);
  int* tperm  = (int*) take((size_t)N*4);

  hipMemsetAsync(degp, 0, (size_t)N*16*4, stream);
  hipMemsetAsync(tcnt, 0, 256, stream);

  int nb_n4 = (N + 1023)/1024, nb_e = (E + 255)/256;
  int nb_s  = (N + 255)/256;
  k_hist4<<<nb_n4, 256, 0, stream>>>(node_type, tcnt, N);
  k_deg<<<nb_e, 256, 0, stream>>>(dstp, degp, rank, E);
  k_toff<<<1, 64, 0, stream>>>(tcnt, toff, tcur);
  k_scanA<<<nb_s, 256, 0, stream>>>(degp, rp, bsum, N);
  k_scanB<<<1, 1024, 0, stream>>>(bsum, nb_s);
  k_scanC<<<nb_s, 256, 0, stream>>>(rp, bsum, N, E);
  k_scatter2<<<nb_n4, 256, 0, stream>>>(node_type, tcur, tperm, N);
  k_fill2<<<nb_e, 256, 0, stream>>>(srcp, dstp, edge_type, rp, rank, packed, E);

  // combined weights for both layers
  k_prepw<<<dim3(NCOL*T_HD/256, T_NT, T_L), 256, 0, stream>>>(
      kw, qw, vw, kb, qb, vb, rel_att, rel_msg, Ball, biasall);

  dim3 gg((N + 63)/64, T_NT);
  k_typed_gemm<1><<<gg, 256, 0, stream>>>(node_feature, tperm, toff, adapt_w, adapt_b, h0, nullptr, nullptr);

  for (int l = 0; l < T_L; ++l){
    size_t wo = (size_t)l * T_NT * T_HD * T_HD;
    size_t bo = (size_t)l * T_NT * T_HD;
    k_qkvm<<<gg, 256, 0, stream>>>(h0, tperm, toff,
        Ball + (size_t)l*T_NT*NCOL*T_HD, biasall + (size_t)l*T_NT*NCOL,
        kB, qt, mtp);
    k_edge_attn<<<2048, 256, 0, stream>>>(kB, qt, mtp, rp, packed, rel_pri + (size_t)l*T_R*T_H, resb, N);
    k_typed_gemm<3><<<gg, 256, 0, stream>>>(resb, tperm, toff, aw+wo, ab+bo,
        (l == T_L-1) ? (float*)d_out : h0, h0, skipp + l*T_NT);
  }
}

// Round 8
// 549.683 us; speedup vs baseline: 15.8779x; 1.1548x over previous
//
#include <hip/hip_runtime.h>

#define T_NT 4
#define T_R  5
#define T_H  4
#define T_DK 32
#define T_HD 128
#define T_L  2
#define NCOL 1408   // 128 (k) + 640 (qt) + 640 (mtp)

typedef unsigned short u16;
typedef __bf16 bf8_t __attribute__((ext_vector_type(8)));
typedef float f4_t __attribute__((ext_vector_type(4)));

__device__ __forceinline__ float bf2f(u16 u){
  union { float f; unsigned int i; } v; v.i = ((unsigned int)u) << 16; return v.f;
}
__device__ __forceinline__ float blo(unsigned u){
  union { float f; unsigned int i; } v; v.i = u << 16; return v.f;
}
__device__ __forceinline__ float bhi(unsigned u){
  union { float f; unsigned int i; } v; v.i = u & 0xffff0000u; return v.f;
}
__device__ __forceinline__ u16 f2bf(float f){
  union { float f; unsigned int i; } v; v.f = f;
  unsigned int x = v.i;
  return (u16)((x + 0x7fffu + ((x >> 16) & 1u)) >> 16);
}
__device__ __forceinline__ float gelu_f(float x){
  float x3 = x*x*x;
  return 0.5f * x * (1.f + tanhf(0.7978845608028654f * (x + 0.044715f * x3)));
}

// ---------------- CSR / bucket build ----------------
__global__ void k_hist4(const int* __restrict__ key, int* __restrict__ cnt, int n){
  __shared__ int c[T_NT];
  int tid = threadIdx.x;
  if (tid < T_NT) c[tid] = 0;
  __syncthreads();
  int base = blockIdx.x*1024;
#pragma unroll
  for (int j=0;j<4;j++){
    int i = base + tid + j*256;
    if (i < n) atomicAdd(&c[key[i]], 1);
  }
  __syncthreads();
  if (tid < T_NT) atomicAdd(&cnt[tid], c[tid]);
}

__global__ void k_toff(const int* __restrict__ cnt, int* __restrict__ off, int* __restrict__ tcur){
  if (threadIdx.x == 0){
    off[0] = 0;
    for (int t = 0; t < T_NT; ++t) off[t+1] = off[t] + cnt[t];
    for (int t = 0; t < T_NT; ++t) tcur[t] = off[t];
  }
}

__global__ void k_scatter2(const int* __restrict__ nt, int* __restrict__ tcur,
                           int* __restrict__ perm, int n){
  __shared__ int lc[T_NT], lb[T_NT];
  int tid = threadIdx.x;
  if (tid < T_NT) lc[tid] = 0;
  __syncthreads();
  int base = blockIdx.x*1024;
  int t[4], lr[4];
#pragma unroll
  for (int j=0;j<4;j++){
    int i = base + tid + j*256;
    if (i < n){ t[j] = nt[i]; lr[j] = atomicAdd(&lc[t[j]], 1); }
    else t[j] = -1;
  }
  __syncthreads();
  if (tid < T_NT) lb[tid] = atomicAdd(&tcur[tid], lc[tid]);
  __syncthreads();
#pragma unroll
  for (int j=0;j<4;j++){
    if (t[j] >= 0) perm[lb[t[j]] + lr[j]] = base + tid + j*256;
  }
}

__global__ void k_deg(const int* __restrict__ dstp, int* __restrict__ degp,
                      int* __restrict__ rank, int n){
  int i = blockIdx.x*256 + threadIdx.x;
  if (i < n) rank[i] = atomicAdd(&degp[(size_t)dstp[i] << 4], 1);
}

__global__ void k_scanA(const int* __restrict__ degp, int* __restrict__ rp,
                        int* __restrict__ bsum, int n){
  __shared__ int buf[256];
  int tid = threadIdx.x;
  int i = blockIdx.x*256 + tid;
  int v = (i < n) ? degp[(size_t)i << 4] : 0;
  buf[tid] = v;
  __syncthreads();
  for (int off = 1; off < 256; off <<= 1){
    int add = (tid >= off) ? buf[tid - off] : 0;
    __syncthreads();
    buf[tid] += add;
    __syncthreads();
  }
  if (i < n) rp[i] = buf[tid] - v;
  if (tid == 255) bsum[blockIdx.x] = buf[255];
}
__global__ void k_scanB(int* __restrict__ bsum, int nb){
  __shared__ int buf[1024];
  int tid = threadIdx.x;
  int v = (tid < nb) ? bsum[tid] : 0;
  buf[tid] = v;
  __syncthreads();
  for (int off = 1; off < 1024; off <<= 1){
    int add = (tid >= off) ? buf[tid - off] : 0;
    __syncthreads();
    buf[tid] += add;
    __syncthreads();
  }
  if (tid < nb) bsum[tid] = buf[tid] - v;
}
__global__ void k_scanC(int* __restrict__ rp, const int* __restrict__ bsum,
                        int n, int E){
  int i = blockIdx.x*256 + threadIdx.x;
  if (i < n) rp[i] += bsum[blockIdx.x];
  if (i == 0) rp[n] = E;
}

__global__ void k_fill2(const int* __restrict__ srcp, const int* __restrict__ dstp,
                        const int* __restrict__ etp, const int* __restrict__ rp,
                        const int* __restrict__ rank, int* __restrict__ packed, int n){
  int i = blockIdx.x*256 + threadIdx.x;
  if (i < n){
    int d = dstp[i];
    packed[rp[d] + rank[i]] = srcp[i] | (etp[i] << 17);
  }
}

// ---------------- combined-weight prep ----------------
// k-part transpose copy + kb bias + qt/mtp biases (all tiny)
__global__ void k_prepmisc(const float* __restrict__ kw, const float* __restrict__ kb,
                           const float* __restrict__ qb, const float* __restrict__ vb,
                           const float* __restrict__ rel_att, const float* __restrict__ rel_msg,
                           const float* __restrict__ rel_pri,
                           u16* __restrict__ Ball, float* __restrict__ biasall)
{
  const float isd = 0.17677669529663687f;
  int idx = blockIdx.x*256 + threadIdx.x;
  if (idx < T_L*T_NT*T_HD*T_HD){
    int col = idx & 127, k = (idx >> 7) & 127, lt = idx >> 14;
    Ball[((size_t)lt*NCOL + col)*T_HD + k] = f2bf(kw[((size_t)lt*T_HD + k)*T_HD + col]);
    if (k == 0) biasall[(size_t)lt*NCOL + col] = kb[(size_t)lt*T_HD + col];
    return;
  }
  int b = idx - T_L*T_NT*T_HD*T_HD;
  if (b >= T_L*T_NT*1280) return;
  int lt = b / 1280, cc = b % 1280;
  int l = lt >> 2;
  int qv = cc >= 640, rem = cc - qv*640;
  int r = rem >> 7, hd = rem & 127, h = hd >> 5, o = hd & 31;
  float s = 0.f;
  if (!qv){
    const float* Ar = rel_att + ((((size_t)l*T_R + r)*T_H + h)*T_DK + o)*T_DK;
    const float* qbr = qb + (size_t)lt*T_HD + h*T_DK;
#pragma unroll
    for (int j = 0; j < 32; ++j) s += qbr[j] * Ar[j];
    s *= rel_pri[((size_t)l*T_R + r)*T_H + h] * isd;
  } else {
    const float* Mr = rel_msg + (((size_t)l*T_R + r)*T_H + h)*T_DK*T_DK + o;
    const float* vbr = vb + (size_t)lt*T_HD + h*T_DK;
#pragma unroll
    for (int i = 0; i < 32; ++i) s += vbr[i] * Mr[i*T_DK];
  }
  biasall[(size_t)lt*NCOL + 128 + qv*640 + r*128 + h*32 + o] = s;
}

// qt/mtp combined weights: block = (qv*4+h, t, l). LDS-staged, reg-tiled.
__global__ __launch_bounds__(256)
void k_prepqv(const float* __restrict__ qw, const float* __restrict__ vw,
              const float* __restrict__ rel_att, const float* __restrict__ rel_msg,
              const float* __restrict__ rel_pri, u16* __restrict__ Ball)
{
  __shared__ float Ws[T_HD*33];
  __shared__ float As_[T_R*32*36];
  const float isd = 0.17677669529663687f;
  int h = blockIdx.x & 3, qv = blockIdx.x >> 2;
  int t = blockIdx.y, l = blockIdx.z;
  int lt = l*T_NT + t;
  int tid = threadIdx.x;
  const float* W = (qv ? vw : qw) + (size_t)lt*T_HD*T_HD;
  const float* rel = (qv ? rel_msg : rel_att);
  // stage W column-slice [128][32] -> Ws[k][j] (pad 33)
#pragma unroll
  for (int i = 0; i < 16; ++i){
    int idx = tid + i*256;
    int j = idx & 31, k = idx >> 5;
    Ws[k*33 + j] = W[(size_t)k*T_HD + h*T_DK + j];
  }
  // stage A[r][o][c]: q -> direct (o=i,c=j), v -> transposed (o=j,c=i). pad 36.
#pragma unroll
  for (int i = 0; i < 20; ++i){
    int idx = tid + i*256;
    int bcol = idx & 31, a = (idx >> 5) & 31, r = idx >> 10;
    float wv = rel[((((size_t)l*T_R + r)*T_H + h)*T_DK + a)*T_DK + bcol];
    if (qv) As_[r*1152 + bcol*36 + a] = wv;
    else    As_[r*1152 + a*36 + bcol] = wv;
  }
  __syncthreads();
  int k = tid & 127, io = tid >> 7;
  float Wrow[32];
#pragma unroll
  for (int c = 0; c < 32; ++c) Wrow[c] = Ws[k*33 + c];
  for (int r = 0; r < T_R; ++r){
    float scale = qv ? 1.f : rel_pri[((size_t)l*T_R + r)*T_H + h] * isd;
#pragma unroll
    for (int i2 = 0; i2 < 16; ++i2){
      int o = i2*2 + io;
      const float4* ap = (const float4*)&As_[r*1152 + o*36];
      float acc = 0.f;
#pragma unroll
      for (int c4 = 0; c4 < 8; ++c4){
        float4 a4 = ap[c4];
        acc += Wrow[c4*4+0]*a4.x + Wrow[c4*4+1]*a4.y + Wrow[c4*4+2]*a4.z + Wrow[c4*4+3]*a4.w;
      }
      int col = 128 + qv*640 + r*128 + h*32 + o;
      Ball[((size_t)lt*NCOL + col)*T_HD + k] = f2bf(acc*scale);
    }
  }
}

// ---------------- fused per-type MFMA GEMM: h -> {kB, qt, mtp} ----------------
__global__ __launch_bounds__(256)
void k_qkvm(const float* __restrict__ X, const int* __restrict__ tperm,
            const int* __restrict__ toff, const u16* __restrict__ Ball,
            const float* __restrict__ biasall,
            u16* __restrict__ kB, u16* __restrict__ qt, u16* __restrict__ mtp)
{
  __shared__ u16 As[64*128];
  __shared__ int rows_s[64];
  int t = blockIdx.y;
  int lo = toff[t], cnt = toff[t+1] - lo;
  int base = (int)blockIdx.x * 64;
  if (base >= cnt) return;
  int tid = threadIdx.x;
  if (tid < 64) rows_s[tid] = (base + tid < cnt) ? tperm[lo + base + tid] : -1;
  __syncthreads();
#pragma unroll
  for (int it = 0; it < 4; ++it){
    int chunk = tid + it*256;
    int row = chunk >> 4, c8 = (chunk & 15) << 3;
    int node = rows_s[row];
    uint4 o = make_uint4(0,0,0,0);
    if (node >= 0){
      const float* src = X + (size_t)node*T_HD + c8;
      float4 f0 = *(const float4*)src;
      float4 f1 = *(const float4*)(src + 4);
      o.x = (unsigned)f2bf(f0.x) | ((unsigned)f2bf(f0.y) << 16);
      o.y = (unsigned)f2bf(f0.z) | ((unsigned)f2bf(f0.w) << 16);
      o.z = (unsigned)f2bf(f1.x) | ((unsigned)f2bf(f1.y) << 16);
      o.w = (unsigned)f2bf(f1.z) | ((unsigned)f2bf(f1.w) << 16);
    }
    int off16 = (row*128 + c8) ^ ((row & 7) << 3);
    *(uint4*)&As[off16] = o;
  }
  __syncthreads();

  int wid = tid >> 6, lane = tid & 63;
  int lr = lane & 15, lg = lane >> 4;
  bf8_t a[4][4];
#pragma unroll
  for (int rs = 0; rs < 4; ++rs)
#pragma unroll
    for (int kk = 0; kk < 4; ++kk){
      int row = rs*16 + lr;
      int off16 = (row*128 + kk*32 + lg*8) ^ ((row & 7) << 3);
      a[rs][kk] = *(const bf8_t*)&As[off16];
    }
  int nod[4][4];
#pragma unroll
  for (int rs = 0; rs < 4; ++rs)
#pragma unroll
    for (int j = 0; j < 4; ++j)
      nod[rs][j] = rows_s[rs*16 + lg*4 + j];

  const u16* Bt = Ball + (size_t)t * NCOL * T_HD;
  const float* biast = biasall + (size_t)t * NCOL;

  for (int c = wid; c < NCOL/16; c += 4){
    int col = c*16 + lr;
    const u16* bp = Bt + (size_t)col*T_HD + lg*8;
    bf8_t b0 = *(const bf8_t*)(bp);
    bf8_t b1 = *(const bf8_t*)(bp + 32);
    bf8_t b2 = *(const bf8_t*)(bp + 64);
    bf8_t b3 = *(const bf8_t*)(bp + 96);
    f4_t acc[4];
#pragma unroll
    for (int rs = 0; rs < 4; ++rs) acc[rs] = (f4_t){0.f,0.f,0.f,0.f};
#pragma unroll
    for (int rs = 0; rs < 4; ++rs){
      acc[rs] = __builtin_amdgcn_mfma_f32_16x16x32_bf16(a[rs][0], b0, acc[rs], 0, 0, 0);
      acc[rs] = __builtin_amdgcn_mfma_f32_16x16x32_bf16(a[rs][1], b1, acc[rs], 0, 0, 0);
      acc[rs] = __builtin_amdgcn_mfma_f32_16x16x32_bf16(a[rs][2], b2, acc[rs], 0, 0, 0);
      acc[rs] = __builtin_amdgcn_mfma_f32_16x16x32_bf16(a[rs][3], b3, acc[rs], 0, 0, 0);
    }
    float bias = biast[col];
    u16* dst; int cofs, stride;
    if (c < 8)       { dst = kB;  cofs = col;        stride = T_HD; }
    else if (c < 48) { dst = qt;  cofs = col - 128;  stride = T_R*T_HD; }
    else             { dst = mtp; cofs = col - 768;  stride = T_R*T_HD; }
#pragma unroll
    for (int rs = 0; rs < 4; ++rs)
#pragma unroll
      for (int j = 0; j < 4; ++j){
        int node = nod[rs][j];
        if (node >= 0) dst[(size_t)node*stride + cofs] = f2bf(acc[rs][j] + bias);
      }
  }
}

// ---------------- per-type gathered GEMM (f32), adapt + update only ----------------
template<int MODE>
__global__ __launch_bounds__(256)
void k_typed_gemm(const float* __restrict__ X,
                  const int* __restrict__ tperm, const int* __restrict__ toff,
                  const float* __restrict__ W, const float* __restrict__ Bi,
                  float* __restrict__ outv,
                  const float* __restrict__ h_in, const float* __restrict__ skipv)
{
  int t = blockIdx.y;
  int lo = toff[t], cnt = toff[t+1] - lo;
  int base = (int)blockIdx.x * 64;
  if (base >= cnt) return;
  __shared__ float As[64][16];
  __shared__ float Bs[16][128];
  __shared__ int rows_s[64];
  int tid = threadIdx.x;
  if (tid < 64){
    int m = base + tid;
    rows_s[tid] = (m < cnt) ? tperm[lo + m] : -1;
  }
  __syncthreads();
  float acc[8][4];
#pragma unroll
  for (int i=0;i<8;i++){ acc[i][0]=0.f;acc[i][1]=0.f;acc[i][2]=0.f;acc[i][3]=0.f; }
  int ty = tid >> 5, tx = tid & 31;
  const float* Wt = W + (size_t)t * (T_HD*T_HD);
  for (int k0 = 0; k0 < T_HD; k0 += 16){
#pragma unroll
    for (int j=0;j<4;j++){
      int idx = tid + j*256;
      int m = idx >> 4, kk = idx & 15;
      int row = rows_s[m];
      float v = 0.f;
      if (row >= 0){
        v = X[(size_t)row*T_HD + k0 + kk];
        if (MODE == 3) v = gelu_f(v);
      }
      As[m][kk] = v;
    }
#pragma unroll
    for (int j=0;j<8;j++){
      int idx = tid + j*256;
      int kk = idx >> 7, c = idx & 127;
      Bs[kk][c] = Wt[(size_t)(k0+kk)*T_HD + c];
    }
    __syncthreads();
#pragma unroll
    for (int kk=0;kk<16;kk++){
      float4 bv = *(const float4*)&Bs[kk][tx*4];
#pragma unroll
      for (int i=0;i<8;i++){
        float a = As[ty*8+i][kk];
        acc[i][0] += a*bv.x; acc[i][1] += a*bv.y; acc[i][2] += a*bv.z; acc[i][3] += a*bv.w;
      }
    }
    __syncthreads();
  }
  float sk = 0.f;
  if (MODE == 3) sk = 1.f / (1.f + __expf(-skipv[t]));
#pragma unroll
  for (int i=0;i<8;i++){
    int m = ty*8 + i;
    int row = rows_s[m];
    if (row < 0) continue;
#pragma unroll
    for (int q=0;q<4;q++){
      int c = tx*4 + q;
      float vv = acc[i][q] + Bi[t*T_HD + c];
      if (MODE == 1) vv = tanhf(vv);
      if (MODE == 3) vv = vv*sk + h_in[(size_t)row*T_HD + c]*(1.f - sk);
      outv[(size_t)row*T_HD + c] = vv;
    }
  }
}

// ---------------- per-dst edge attention v2 (pair-packed dims) ----------------
// lane owns dims {2l, 2l+1}; head = lane>>4; 4-stage shfl reduce; pri folded into qt.
__global__ __launch_bounds__(256)
void k_edge_attn2(const u16* __restrict__ kB, const u16* __restrict__ qt,
                  const u16* __restrict__ mtp, const int* __restrict__ rp,
                  const int* __restrict__ packed, float* __restrict__ resb, int n)
{
  int lane = threadIdx.x & 63;
  int wid = (int)blockIdx.x * (blockDim.x >> 6) + (threadIdx.x >> 6);
  int nw = (int)gridDim.x * (blockDim.x >> 6);
  int l2 = lane << 1;
  for (int dst = wid; dst < n; dst += nw){
    int e0 = rp[dst], e1 = rp[dst+1];
    const u16* qrow = qt + (size_t)dst*(T_R*T_HD) + l2;
    float m = -INFINITY, d = 0.f, a0 = 0.f, a1 = 0.f;
    for (int ei = e0; ei < e1; ++ei){
      int pk = packed[ei];
      int s = pk & 131071;
      int rt = pk >> 17;
      unsigned kk = *(const unsigned*)&kB[(s << 7) + l2];
      unsigned qq = *(const unsigned*)&qrow[rt << 7];
      unsigned mm = *(const unsigned*)&mtp[((s*T_R + rt) << 7) + l2];
      float p = blo(qq)*blo(kk) + bhi(qq)*bhi(kk);
      p += __shfl_xor(p, 1);
      p += __shfl_xor(p, 2);
      p += __shfl_xor(p, 4);
      p += __shfl_xor(p, 8);
      float mn = fmaxf(m, p);
      float sc = __expf(m - mn);
      float w  = __expf(p - mn);
      m = mn;
      d  = d*sc + w;
      a0 = a0*sc + w*blo(mm);
      a1 = a1*sc + w*bhi(mm);
    }
    float inv = 1.f / fmaxf(d, 1e-9f);
    float2 o = make_float2(a0*inv, a1*inv);
    *(float2*)&resb[(size_t)dst*T_HD + l2] = o;
  }
}

extern "C" void kernel_launch(void* const* d_in, const int* in_sizes, int n_in,
                              void* d_out, int out_size, void* d_ws, size_t ws_size,
                              hipStream_t stream)
{
  const float* node_feature = (const float*)d_in[0];
  const int* node_type    = (const int*)d_in[1];
  const int* edge_index   = (const int*)d_in[3];
  const int* edge_type    = (const int*)d_in[4];
  const float* adapt_w = (const float*)d_in[5];
  const float* adapt_b = (const float*)d_in[6];
  const float* kw = (const float*)d_in[7];
  const float* kb = (const float*)d_in[8];
  const float* qw = (const float*)d_in[9];
  const float* qb = (const float*)d_in[10];
  const float* vw = (const float*)d_in[11];
  const float* vb = (const float*)d_in[12];
  const float* aw = (const float*)d_in[13];
  const float* ab = (const float*)d_in[14];
  const float* rel_pri = (const float*)d_in[15];
  const float* rel_att = (const float*)d_in[16];
  const float* rel_msg = (const float*)d_in[17];
  const float* skipp   = (const float*)d_in[18];

  const int N = in_sizes[1];
  const int E = in_sizes[4];
  const int* srcp = edge_index;
  const int* dstp = edge_index + E;

  char* p = (char*)d_ws;
  auto take = [&](size_t bytes)->char*{
    char* r = p; p += (bytes + 255) & ~(size_t)255; return r;
  };
  float* h0   = (float*)take((size_t)N*T_HD*4);
  float* resb = (float*)take((size_t)N*T_HD*4);
  u16*  kB    = (u16*) take((size_t)N*T_HD*2);
  u16*  qt    = (u16*) take((size_t)N*T_R*T_HD*2);
  u16*  mtp   = (u16*) take((size_t)N*T_R*T_HD*2);
  u16*  Ball  = (u16*) take((size_t)T_L*T_NT*NCOL*T_HD*2);
  float* biasall = (float*)take((size_t)T_L*T_NT*NCOL*4);
  int* degp   = (int*) take((size_t)N*16*4);
  int* rp     = (int*) take(((size_t)N+1)*4);
  int* rank   = (int*) take((size_t)E*4);
  int* packed = (int*) take((size_t)E*4);
  int* tcnt   = (int*) take(256);
  int* toff   = (int*) take(256);
  int* tcur   = (int*) take(256);
  int* bsum   = (int*) take(1024);
  int* tperm  = (int*) take((size_t)N*4);

  hipMemsetAsync(degp, 0, (size_t)N*16*4, stream);
  hipMemsetAsync(tcnt, 0, 256, stream);

  int nb_n4 = (N + 1023)/1024, nb_e = (E + 255)/256;
  int nb_s  = (N + 255)/256;
  k_hist4<<<nb_n4, 256, 0, stream>>>(node_type, tcnt, N);
  k_deg<<<nb_e, 256, 0, stream>>>(dstp, degp, rank, E);
  k_toff<<<1, 64, 0, stream>>>(tcnt, toff, tcur);
  k_scanA<<<nb_s, 256, 0, stream>>>(degp, rp, bsum, N);
  k_scanB<<<1, 1024, 0, stream>>>(bsum, nb_s);
  k_scanC<<<nb_s, 256, 0, stream>>>(rp, bsum, N, E);
  k_scatter2<<<nb_n4, 256, 0, stream>>>(node_type, tcur, tperm, N);
  k_fill2<<<nb_e, 256, 0, stream>>>(srcp, dstp, edge_type, rp, rank, packed, E);

  // combined weights (biases + k-part transpose; then LDS-staged qt/mtp weights)
  int misc_total = T_L*T_NT*T_HD*T_HD + T_L*T_NT*1280;
  k_prepmisc<<<(misc_total + 255)/256, 256, 0, stream>>>(
      kw, kb, qb, vb, rel_att, rel_msg, rel_pri, Ball, biasall);
  k_prepqv<<<dim3(8, T_NT, T_L), 256, 0, stream>>>(
      qw, vw, rel_att, rel_msg, rel_pri, Ball);

  dim3 gg((N + 63)/64, T_NT);
  k_typed_gemm<1><<<gg, 256, 0, stream>>>(node_feature, tperm, toff, adapt_w, adapt_b, h0, nullptr, nullptr);

  for (int l = 0; l < T_L; ++l){
    size_t wo = (size_t)l * T_NT * T_HD * T_HD;
    size_t bo = (size_t)l * T_NT * T_HD;
    k_qkvm<<<gg, 256, 0, stream>>>(h0, tperm, toff,
        Ball + (size_t)l*T_NT*NCOL*T_HD, biasall + (size_t)l*T_NT*NCOL,
        kB, qt, mtp);
    k_edge_attn2<<<2048, 256, 0, stream>>>(kB, qt, mtp, rp, packed, resb, N);
    k_typed_gemm<3><<<gg, 256, 0, stream>>>(resb, tperm, toff, aw+wo, ab+bo,
        (l == T_L-1) ? (float*)d_out : h0, h0, skipp + l*T_NT);
  }
}

// Round 9
// 514.456 us; speedup vs baseline: 16.9651x; 1.0685x over previous
//
#include <hip/hip_runtime.h>

#define T_NT 4
#define T_R  5
#define T_H  4
#define T_DK 32
#define T_HD 128
#define T_L  2
#define NCOL 1408   // 128 (k) + 640 (qt) + 640 (mtp)

typedef unsigned short u16;
typedef __bf16 bf8_t __attribute__((ext_vector_type(8)));
typedef float f4_t __attribute__((ext_vector_type(4)));

__device__ __forceinline__ float bf2f(u16 u){
  union { float f; unsigned int i; } v; v.i = ((unsigned int)u) << 16; return v.f;
}
__device__ __forceinline__ float blo(unsigned u){
  union { float f; unsigned int i; } v; v.i = u << 16; return v.f;
}
__device__ __forceinline__ float bhi(unsigned u){
  union { float f; unsigned int i; } v; v.i = u & 0xffff0000u; return v.f;
}
__device__ __forceinline__ u16 f2bf(float f){
  union { float f; unsigned int i; } v; v.f = f;
  unsigned int x = v.i;
  return (u16)((x + 0x7fffu + ((x >> 16) & 1u)) >> 16);
}
__device__ __forceinline__ float gelu_f(float x){
  float x3 = x*x*x;
  return 0.5f * x * (1.f + tanhf(0.7978845608028654f * (x + 0.044715f * x3)));
}

// ---------------- CSR / bucket build ----------------
__global__ void k_hist4(const int* __restrict__ key, int* __restrict__ cnt, int n){
  __shared__ int c[T_NT];
  int tid = threadIdx.x;
  if (tid < T_NT) c[tid] = 0;
  __syncthreads();
  int base = blockIdx.x*1024;
#pragma unroll
  for (int j=0;j<4;j++){
    int i = base + tid + j*256;
    if (i < n) atomicAdd(&c[key[i]], 1);
  }
  __syncthreads();
  if (tid < T_NT) atomicAdd(&cnt[tid], c[tid]);
}

__global__ void k_toff(const int* __restrict__ cnt, int* __restrict__ off, int* __restrict__ tcur){
  if (threadIdx.x == 0){
    off[0] = 0;
    for (int t = 0; t < T_NT; ++t) off[t+1] = off[t] + cnt[t];
    for (int t = 0; t < T_NT; ++t) tcur[t] = off[t];
  }
}

// builds perm (bucket pos -> node) AND iperm (node -> bucket pos)
__global__ void k_scatter2(const int* __restrict__ nt, int* __restrict__ tcur,
                           int* __restrict__ perm, int* __restrict__ iperm, int n){
  __shared__ int lc[T_NT], lb[T_NT];
  int tid = threadIdx.x;
  if (tid < T_NT) lc[tid] = 0;
  __syncthreads();
  int base = blockIdx.x*1024;
  int t[4], lr[4];
#pragma unroll
  for (int j=0;j<4;j++){
    int i = base + tid + j*256;
    if (i < n){ t[j] = nt[i]; lr[j] = atomicAdd(&lc[t[j]], 1); }
    else t[j] = -1;
  }
  __syncthreads();
  if (tid < T_NT) lb[tid] = atomicAdd(&tcur[tid], lc[tid]);
  __syncthreads();
#pragma unroll
  for (int j=0;j<4;j++){
    if (t[j] >= 0){
      int node = base + tid + j*256;
      int pos = lb[t[j]] + lr[j];
      perm[pos] = node;
      iperm[node] = pos;
    }
  }
}

// degree histogram over dst BUCKET positions; captures per-edge rank
__global__ void k_deg(const int* __restrict__ dstp, const int* __restrict__ iperm,
                      int* __restrict__ degp, int* __restrict__ rank, int n){
  int i = blockIdx.x*256 + threadIdx.x;
  if (i < n) rank[i] = atomicAdd(&degp[(size_t)iperm[dstp[i]] << 4], 1);
}

__global__ void k_scanA(const int* __restrict__ degp, int* __restrict__ rp,
                        int* __restrict__ bsum, int n){
  __shared__ int buf[256];
  int tid = threadIdx.x;
  int i = blockIdx.x*256 + tid;
  int v = (i < n) ? degp[(size_t)i << 4] : 0;
  buf[tid] = v;
  __syncthreads();
  for (int off = 1; off < 256; off <<= 1){
    int add = (tid >= off) ? buf[tid - off] : 0;
    __syncthreads();
    buf[tid] += add;
    __syncthreads();
  }
  if (i < n) rp[i] = buf[tid] - v;
  if (tid == 255) bsum[blockIdx.x] = buf[255];
}
__global__ void k_scanB(int* __restrict__ bsum, int nb){
  __shared__ int buf[1024];
  int tid = threadIdx.x;
  int v = (tid < nb) ? bsum[tid] : 0;
  buf[tid] = v;
  __syncthreads();
  for (int off = 1; off < 1024; off <<= 1){
    int add = (tid >= off) ? buf[tid - off] : 0;
    __syncthreads();
    buf[tid] += add;
    __syncthreads();
  }
  if (tid < nb) bsum[tid] = buf[tid] - v;
}
__global__ void k_scanC(int* __restrict__ rp, const int* __restrict__ bsum,
                        int n, int E){
  int i = blockIdx.x*256 + threadIdx.x;
  if (i < n) rp[i] += bsum[blockIdx.x];
  if (i == 0) rp[n] = E;
}

// edge placement: endpoints remapped to bucket positions
__global__ void k_fill2(const int* __restrict__ srcp, const int* __restrict__ dstp,
                        const int* __restrict__ etp, const int* __restrict__ iperm,
                        const int* __restrict__ rp, const int* __restrict__ rank,
                        int* __restrict__ packed, int n){
  int i = blockIdx.x*256 + threadIdx.x;
  if (i < n){
    int d = iperm[dstp[i]];
    packed[rp[d] + rank[i]] = iperm[srcp[i]] | (etp[i] << 17);   // N < 2^17
  }
}

// ---------------- combined-weight prep ----------------
__global__ void k_prepmisc(const float* __restrict__ kw, const float* __restrict__ kb,
                           const float* __restrict__ qb, const float* __restrict__ vb,
                           const float* __restrict__ rel_att, const float* __restrict__ rel_msg,
                           const float* __restrict__ rel_pri,
                           u16* __restrict__ Ball, float* __restrict__ biasall)
{
  const float isd = 0.17677669529663687f;
  int idx = blockIdx.x*256 + threadIdx.x;
  if (idx < T_L*T_NT*T_HD*T_HD){
    int col = idx & 127, k = (idx >> 7) & 127, lt = idx >> 14;
    Ball[((size_t)lt*NCOL + col)*T_HD + k] = f2bf(kw[((size_t)lt*T_HD + k)*T_HD + col]);
    if (k == 0) biasall[(size_t)lt*NCOL + col] = kb[(size_t)lt*T_HD + col];
    return;
  }
  int b = idx - T_L*T_NT*T_HD*T_HD;
  if (b >= T_L*T_NT*1280) return;
  int lt = b / 1280, cc = b % 1280;
  int l = lt >> 2;
  int qv = cc >= 640, rem = cc - qv*640;
  int r = rem >> 7, hd = rem & 127, h = hd >> 5, o = hd & 31;
  float s = 0.f;
  if (!qv){
    const float* Ar = rel_att + ((((size_t)l*T_R + r)*T_H + h)*T_DK + o)*T_DK;
    const float* qbr = qb + (size_t)lt*T_HD + h*T_DK;
#pragma unroll
    for (int j = 0; j < 32; ++j) s += qbr[j] * Ar[j];
    s *= rel_pri[((size_t)l*T_R + r)*T_H + h] * isd;
  } else {
    const float* Mr = rel_msg + (((size_t)l*T_R + r)*T_H + h)*T_DK*T_DK + o;
    const float* vbr = vb + (size_t)lt*T_HD + h*T_DK;
#pragma unroll
    for (int i = 0; i < 32; ++i) s += vbr[i] * Mr[i*T_DK];
  }
  biasall[(size_t)lt*NCOL + 128 + qv*640 + r*128 + h*32 + o] = s;
}

__global__ __launch_bounds__(256)
void k_prepqv(const float* __restrict__ qw, const float* __restrict__ vw,
              const float* __restrict__ rel_att, const float* __restrict__ rel_msg,
              const float* __restrict__ rel_pri, u16* __restrict__ Ball)
{
  __shared__ float Ws[T_HD*33];
  __shared__ float As_[T_R*32*36];
  const float isd = 0.17677669529663687f;
  int h = blockIdx.x & 3, qv = blockIdx.x >> 2;
  int t = blockIdx.y, l = blockIdx.z;
  int lt = l*T_NT + t;
  int tid = threadIdx.x;
  const float* W = (qv ? vw : qw) + (size_t)lt*T_HD*T_HD;
  const float* rel = (qv ? rel_msg : rel_att);
#pragma unroll
  for (int i = 0; i < 16; ++i){
    int idx = tid + i*256;
    int j = idx & 31, k = idx >> 5;
    Ws[k*33 + j] = W[(size_t)k*T_HD + h*T_DK + j];
  }
#pragma unroll
  for (int i = 0; i < 20; ++i){
    int idx = tid + i*256;
    int bcol = idx & 31, a = (idx >> 5) & 31, r = idx >> 10;
    float wv = rel[((((size_t)l*T_R + r)*T_H + h)*T_DK + a)*T_DK + bcol];
    if (qv) As_[r*1152 + bcol*36 + a] = wv;
    else    As_[r*1152 + a*36 + bcol] = wv;
  }
  __syncthreads();
  int k = tid & 127, io = tid >> 7;
  float Wrow[32];
#pragma unroll
  for (int c = 0; c < 32; ++c) Wrow[c] = Ws[k*33 + c];
  for (int r = 0; r < T_R; ++r){
    float scale = qv ? 1.f : rel_pri[((size_t)l*T_R + r)*T_H + h] * isd;
#pragma unroll
    for (int i2 = 0; i2 < 16; ++i2){
      int o = i2*2 + io;
      const float4* ap = (const float4*)&As_[r*1152 + o*36];
      float acc = 0.f;
#pragma unroll
      for (int c4 = 0; c4 < 8; ++c4){
        float4 a4 = ap[c4];
        acc += Wrow[c4*4+0]*a4.x + Wrow[c4*4+1]*a4.y + Wrow[c4*4+2]*a4.z + Wrow[c4*4+3]*a4.w;
      }
      int col = 128 + qv*640 + r*128 + h*32 + o;
      Ball[((size_t)lt*NCOL + col)*T_HD + k] = f2bf(acc*scale);
    }
  }
}

// ---------------- fused per-type MFMA GEMM: h(bucket) -> {kB, qt, mtp}(bucket) ----------------
// operand-swapped MFMA: D = B^T*A^T layout -> lane owns node=lane&15, 4 consecutive cols.
__global__ __launch_bounds__(256)
void k_qkvm(const float* __restrict__ X, const int* __restrict__ toff,
            const u16* __restrict__ Ball, const float* __restrict__ biasall,
            u16* __restrict__ kB, u16* __restrict__ qt, u16* __restrict__ mtp)
{
  __shared__ u16 As[64*128];
  int t = blockIdx.y;
  int lo = toff[t], cnt = toff[t+1] - lo;
  int base = (int)blockIdx.x * 64;
  if (base >= cnt) return;
  int tid = threadIdx.x;
  // stage A tile from bucket-contiguous rows (f32 -> bf16), XOR-swizzled
#pragma unroll
  for (int it = 0; it < 4; ++it){
    int chunk = tid + it*256;
    int row = chunk >> 4, c8 = (chunk & 15) << 3;
    uint4 o = make_uint4(0,0,0,0);
    if (base + row < cnt){
      const float* src = X + (size_t)(lo + base + row)*T_HD + c8;
      float4 f0 = *(const float4*)src;
      float4 f1 = *(const float4*)(src + 4);
      o.x = (unsigned)f2bf(f0.x) | ((unsigned)f2bf(f0.y) << 16);
      o.y = (unsigned)f2bf(f0.z) | ((unsigned)f2bf(f0.w) << 16);
      o.z = (unsigned)f2bf(f1.x) | ((unsigned)f2bf(f1.y) << 16);
      o.w = (unsigned)f2bf(f1.z) | ((unsigned)f2bf(f1.w) << 16);
    }
    int off16 = (row*128 + c8) ^ ((row & 7) << 3);
    *(uint4*)&As[off16] = o;
  }
  __syncthreads();

  int wid = tid >> 6, lane = tid & 63;
  int lr = lane & 15, lg = lane >> 4;
  bf8_t a[4][4];
#pragma unroll
  for (int rs = 0; rs < 4; ++rs)
#pragma unroll
    for (int kk = 0; kk < 4; ++kk){
      int row = rs*16 + lr;
      int off16 = (row*128 + kk*32 + lg*8) ^ ((row & 7) << 3);
      a[rs][kk] = *(const bf8_t*)&As[off16];
    }

  const u16* Bt = Ball + (size_t)t * NCOL * T_HD;
  const float* biast = biasall + (size_t)t * NCOL;

  for (int c = wid; c < NCOL/16; c += 4){
    int col = c*16 + lr;
    const u16* bp = Bt + (size_t)col*T_HD + lg*8;
    bf8_t b0 = *(const bf8_t*)(bp);
    bf8_t b1 = *(const bf8_t*)(bp + 32);
    bf8_t b2 = *(const bf8_t*)(bp + 64);
    bf8_t b3 = *(const bf8_t*)(bp + 96);
    f4_t acc[4];
#pragma unroll
    for (int rs = 0; rs < 4; ++rs) acc[rs] = (f4_t){0.f,0.f,0.f,0.f};
#pragma unroll
    for (int rs = 0; rs < 4; ++rs){
      acc[rs] = __builtin_amdgcn_mfma_f32_16x16x32_bf16(b0, a[rs][0], acc[rs], 0, 0, 0);
      acc[rs] = __builtin_amdgcn_mfma_f32_16x16x32_bf16(b1, a[rs][1], acc[rs], 0, 0, 0);
      acc[rs] = __builtin_amdgcn_mfma_f32_16x16x32_bf16(b2, a[rs][2], acc[rs], 0, 0, 0);
      acc[rs] = __builtin_amdgcn_mfma_f32_16x16x32_bf16(b3, a[rs][3], acc[rs], 0, 0, 0);
    }
    // D layout (swapped): node = rs*16 + lr, cols = c*16 + lg*4 + {0..3}
    float4 bias4 = *(const float4*)&biast[c*16 + lg*4];
    u16* dst; int cofs, stride;
    if (c < 8)       { dst = kB;  cofs = c*16 + lg*4;        stride = T_HD; }
    else if (c < 48) { dst = qt;  cofs = c*16 + lg*4 - 128;  stride = T_R*T_HD; }
    else             { dst = mtp; cofs = c*16 + lg*4 - 768;  stride = T_R*T_HD; }
#pragma unroll
    for (int rs = 0; rs < 4; ++rs){
      int nl = rs*16 + lr;
      if (base + nl < cnt){
        uint2 o;
        o.x = (unsigned)f2bf(acc[rs][0] + bias4.x) | ((unsigned)f2bf(acc[rs][1] + bias4.y) << 16);
        o.y = (unsigned)f2bf(acc[rs][2] + bias4.z) | ((unsigned)f2bf(acc[rs][3] + bias4.w) << 16);
        *(uint2*)&dst[(size_t)(lo + base + nl)*stride + cofs] = o;
      }
    }
  }
}

// ---------------- per-type gathered GEMM (f32), adapt + update ----------------
// MODE 1: tanh epilogue, GIN=1 (gather X rows via tperm), linear out (bucket)
// MODE 3: gelu-on-input + gated residual; GIN=0 (linear bucket in); SOUT: scatter out via tperm
template<int MODE, int GIN, int SOUT>
__global__ __launch_bounds__(256)
void k_typed_gemm(const float* __restrict__ X,
                  const int* __restrict__ tperm, const int* __restrict__ toff,
                  const float* __restrict__ W, const float* __restrict__ Bi,
                  float* __restrict__ outv,
                  const float* __restrict__ h_in, const float* __restrict__ skipv)
{
  int t = blockIdx.y;
  int lo = toff[t], cnt = toff[t+1] - lo;
  int base = (int)blockIdx.x * 64;
  if (base >= cnt) return;
  __shared__ float As[64][16];
  __shared__ float Bs[16][128];
  __shared__ int rows_s[64];
  int tid = threadIdx.x;
  if (GIN || SOUT){
    if (tid < 64) rows_s[tid] = (base + tid < cnt) ? tperm[lo + base + tid] : -1;
    __syncthreads();
  }
  float acc[8][4];
#pragma unroll
  for (int i=0;i<8;i++){ acc[i][0]=0.f;acc[i][1]=0.f;acc[i][2]=0.f;acc[i][3]=0.f; }
  int ty = tid >> 5, tx = tid & 31;
  const float* Wt = W + (size_t)t * (T_HD*T_HD);
  for (int k0 = 0; k0 < T_HD; k0 += 16){
#pragma unroll
    for (int j=0;j<4;j++){
      int idx = tid + j*256;
      int m = idx >> 4, kk = idx & 15;
      float v = 0.f;
      if (base + m < cnt){
        if (GIN){
          int row = rows_s[m];
          v = X[(size_t)row*T_HD + k0 + kk];
        } else {
          v = X[(size_t)(lo + base + m)*T_HD + k0 + kk];
        }
        if (MODE == 3) v = gelu_f(v);
      }
      As[m][kk] = v;
    }
#pragma unroll
    for (int j=0;j<8;j++){
      int idx = tid + j*256;
      int kk = idx >> 7, c = idx & 127;
      Bs[kk][c] = Wt[(size_t)(k0+kk)*T_HD + c];
    }
    __syncthreads();
#pragma unroll
    for (int kk=0;kk<16;kk++){
      float4 bv = *(const float4*)&Bs[kk][tx*4];
#pragma unroll
      for (int i=0;i<8;i++){
        float a = As[ty*8+i][kk];
        acc[i][0] += a*bv.x; acc[i][1] += a*bv.y; acc[i][2] += a*bv.z; acc[i][3] += a*bv.w;
      }
    }
    __syncthreads();
  }
  float sk = 0.f;
  if (MODE == 3) sk = 1.f / (1.f + __expf(-skipv[t]));
#pragma unroll
  for (int i=0;i<8;i++){
    int m = ty*8 + i;
    if (base + m >= cnt) continue;
    size_t opos = SOUT ? (size_t)rows_s[m] : (size_t)(lo + base + m);
#pragma unroll
    for (int q=0;q<4;q++){
      int c = tx*4 + q;
      float vv = acc[i][q] + Bi[t*T_HD + c];
      if (MODE == 1) vv = tanhf(vv);
      if (MODE == 3) vv = vv*sk + h_in[(size_t)(lo + base + m)*T_HD + c]*(1.f - sk);
      outv[opos*T_HD + c] = vv;
    }
  }
}

// ---------------- per-dst edge attention (bucket indices, pair-packed dims) ----------------
__global__ __launch_bounds__(256)
void k_edge_attn2(const u16* __restrict__ kB, const u16* __restrict__ qt,
                  const u16* __restrict__ mtp, const int* __restrict__ rp,
                  const int* __restrict__ packed, float* __restrict__ resb, int n)
{
  int lane = threadIdx.x & 63;
  int wid = (int)blockIdx.x * (blockDim.x >> 6) + (threadIdx.x >> 6);
  int nw = (int)gridDim.x * (blockDim.x >> 6);
  int l2 = lane << 1;
  for (int dst = wid; dst < n; dst += nw){
    int e0 = rp[dst], e1 = rp[dst+1];
    const u16* qrow = qt + (size_t)dst*(T_R*T_HD) + l2;
    float m = -INFINITY, d = 0.f, a0 = 0.f, a1 = 0.f;
    for (int ei = e0; ei < e1; ++ei){
      int pk = packed[ei];
      int s = pk & 131071;
      int rt = pk >> 17;
      unsigned kk = *(const unsigned*)&kB[(s << 7) + l2];
      unsigned qq = *(const unsigned*)&qrow[rt << 7];
      unsigned mm = *(const unsigned*)&mtp[((s*T_R + rt) << 7) + l2];
      float p = blo(qq)*blo(kk) + bhi(qq)*bhi(kk);
      p += __shfl_xor(p, 1);
      p += __shfl_xor(p, 2);
      p += __shfl_xor(p, 4);
      p += __shfl_xor(p, 8);
      float mn = fmaxf(m, p);
      float sc = __expf(m - mn);
      float w  = __expf(p - mn);
      m = mn;
      d  = d*sc + w;
      a0 = a0*sc + w*blo(mm);
      a1 = a1*sc + w*bhi(mm);
    }
    float inv = 1.f / fmaxf(d, 1e-9f);
    float2 o = make_float2(a0*inv, a1*inv);
    *(float2*)&resb[(size_t)dst*T_HD + l2] = o;
  }
}

extern "C" void kernel_launch(void* const* d_in, const int* in_sizes, int n_in,
                              void* d_out, int out_size, void* d_ws, size_t ws_size,
                              hipStream_t stream)
{
  const float* node_feature = (const float*)d_in[0];
  const int* node_type    = (const int*)d_in[1];
  const int* edge_index   = (const int*)d_in[3];
  const int* edge_type    = (const int*)d_in[4];
  const float* adapt_w = (const float*)d_in[5];
  const float* adapt_b = (const float*)d_in[6];
  const float* kw = (const float*)d_in[7];
  const float* kb = (const float*)d_in[8];
  const float* qw = (const float*)d_in[9];
  const float* qb = (const float*)d_in[10];
  const float* vw = (const float*)d_in[11];
  const float* vb = (const float*)d_in[12];
  const float* aw = (const float*)d_in[13];
  const float* ab = (const float*)d_in[14];
  const float* rel_pri = (const float*)d_in[15];
  const float* rel_att = (const float*)d_in[16];
  const float* rel_msg = (const float*)d_in[17];
  const float* skipp   = (const float*)d_in[18];

  const int N = in_sizes[1];
  const int E = in_sizes[4];
  const int* srcp = edge_index;
  const int* dstp = edge_index + E;

  char* p = (char*)d_ws;
  auto take = [&](size_t bytes)->char*{
    char* r = p; p += (bytes + 255) & ~(size_t)255; return r;
  };
  float* h0   = (float*)take((size_t)N*T_HD*4);
  float* resb = (float*)take((size_t)N*T_HD*4);
  u16*  kB    = (u16*) take((size_t)N*T_HD*2);
  u16*  qt    = (u16*) take((size_t)N*T_R*T_HD*2);
  u16*  mtp   = (u16*) take((size_t)N*T_R*T_HD*2);
  u16*  Ball  = (u16*) take((size_t)T_L*T_NT*NCOL*T_HD*2);
  float* biasall = (float*)take((size_t)T_L*T_NT*NCOL*4);
  int* degp   = (int*) take((size_t)N*16*4);
  int* rp     = (int*) take(((size_t)N+1)*4);
  int* rank   = (int*) take((size_t)E*4);
  int* packed = (int*) take((size_t)E*4);
  int* tcnt   = (int*) take(256);
  int* toff   = (int*) take(256);
  int* tcur   = (int*) take(256);
  int* bsum   = (int*) take(1024);
  int* tperm  = (int*) take((size_t)N*4);
  int* iperm  = (int*) take((size_t)N*4);

  hipMemsetAsync(degp, 0, (size_t)N*16*4, stream);
  hipMemsetAsync(tcnt, 0, 256, stream);

  int nb_n4 = (N + 1023)/1024, nb_e = (E + 255)/256;
  int nb_s  = (N + 255)/256;
  k_hist4<<<nb_n4, 256, 0, stream>>>(node_type, tcnt, N);
  k_toff<<<1, 64, 0, stream>>>(tcnt, toff, tcur);
  k_scatter2<<<nb_n4, 256, 0, stream>>>(node_type, tcur, tperm, iperm, N);
  k_deg<<<nb_e, 256, 0, stream>>>(dstp, iperm, degp, rank, E);
  k_scanA<<<nb_s, 256, 0, stream>>>(degp, rp, bsum, N);
  k_scanB<<<1, 1024, 0, stream>>>(bsum, nb_s);
  k_scanC<<<nb_s, 256, 0, stream>>>(rp, bsum, N, E);
  k_fill2<<<nb_e, 256, 0, stream>>>(srcp, dstp, edge_type, iperm, rp, rank, packed, E);

  int misc_total = T_L*T_NT*T_HD*T_HD + T_L*T_NT*1280;
  k_prepmisc<<<(misc_total + 255)/256, 256, 0, stream>>>(
      kw, kb, qb, vb, rel_att, rel_msg, rel_pri, Ball, biasall);
  k_prepqv<<<dim3(8, T_NT, T_L), 256, 0, stream>>>(
      qw, vw, rel_att, rel_msg, rel_pri, Ball);

  dim3 gg((N + 63)/64, T_NT);
  // adapt: h0[bucket] = tanh(node_feature[node] @ adapt_w[t] + adapt_b[t])
  k_typed_gemm<1,1,0><<<gg, 256, 0, stream>>>(node_feature, tperm, toff, adapt_w, adapt_b, h0, nullptr, nullptr);

  for (int l = 0; l < T_L; ++l){
    size_t wo = (size_t)l * T_NT * T_HD * T_HD;
    size_t bo = (size_t)l * T_NT * T_HD;
    k_qkvm<<<gg, 256, 0, stream>>>(h0, toff,
        Ball + (size_t)l*T_NT*NCOL*T_HD, biasall + (size_t)l*T_NT*NCOL,
        kB, qt, mtp);
    k_edge_attn2<<<2048, 256, 0, stream>>>(kB, qt, mtp, rp, packed, resb, N);
    if (l == T_L - 1)
      k_typed_gemm<3,0,1><<<gg, 256, 0, stream>>>(resb, tperm, toff, aw+wo, ab+bo,
          (float*)d_out, h0, skipp + l*T_NT);
    else
      k_typed_gemm<3,0,0><<<gg, 256, 0, stream>>>(resb, tperm, toff, aw+wo, ab+bo,
          h0, h0, skipp + l*T_NT);
  }
}

// Round 10
// 460.621 us; speedup vs baseline: 18.9479x; 1.1169x over previous
//
#include <hip/hip_runtime.h>

#define T_NT 4
#define T_R  5
#define T_H  4
#define T_DK 32
#define T_HD 128
#define T_L  2
#define NCOL 1408   // 128 (k) + 640 (qt) + 640 (mtp)

typedef unsigned short u16;
typedef __bf16 bf8_t __attribute__((ext_vector_type(8)));
typedef float f4_t __attribute__((ext_vector_type(4)));

__device__ __forceinline__ float bf2f(u16 u){
  union { float f; unsigned int i; } v; v.i = ((unsigned int)u) << 16; return v.f;
}
__device__ __forceinline__ float blo(unsigned u){
  union { float f; unsigned int i; } v; v.i = u << 16; return v.f;
}
__device__ __forceinline__ float bhi(unsigned u){
  union { float f; unsigned int i; } v; v.i = u & 0xffff0000u; return v.f;
}
__device__ __forceinline__ u16 f2bf(float f){
  union { float f; unsigned int i; } v; v.f = f;
  unsigned int x = v.i;
  return (u16)((x + 0x7fffu + ((x >> 16) & 1u)) >> 16);
}
__device__ __forceinline__ unsigned pk2(float a, float b){
  return (unsigned)f2bf(a) | ((unsigned)f2bf(b) << 16);
}
__device__ __forceinline__ float gelu_f(float x){
  float x3 = x*x*x;
  return 0.5f * x * (1.f + tanhf(0.7978845608028654f * (x + 0.044715f * x3)));
}
// mem-position -> logical col for the pair-packed layout (see k_qkvm epilogue)
__device__ __forceinline__ int perm_l(int m){
  return (m & ~31) | ((m & 4) << 2) | ((m & 24) >> 1) | (m & 3);
}

// ---------------- CSR / bucket build ----------------
__global__ void k_hist4(const int* __restrict__ key, int* __restrict__ cnt, int n){
  __shared__ int c[T_NT];
  int tid = threadIdx.x;
  if (tid < T_NT) c[tid] = 0;
  __syncthreads();
  int base = blockIdx.x*1024;
#pragma unroll
  for (int j=0;j<4;j++){
    int i = base + tid + j*256;
    if (i < n) atomicAdd(&c[key[i]], 1);
  }
  __syncthreads();
  if (tid < T_NT) atomicAdd(&cnt[tid], c[tid]);
}

__global__ void k_toff(const int* __restrict__ cnt, int* __restrict__ off, int* __restrict__ tcur){
  if (threadIdx.x == 0){
    off[0] = 0;
    for (int t = 0; t < T_NT; ++t) off[t+1] = off[t] + cnt[t];
    for (int t = 0; t < T_NT; ++t) tcur[t] = off[t];
  }
}

__global__ void k_scatter2(const int* __restrict__ nt, int* __restrict__ tcur,
                           int* __restrict__ perm, int* __restrict__ iperm, int n){
  __shared__ int lc[T_NT], lb[T_NT];
  int tid = threadIdx.x;
  if (tid < T_NT) lc[tid] = 0;
  __syncthreads();
  int base = blockIdx.x*1024;
  int t[4], lr[4];
#pragma unroll
  for (int j=0;j<4;j++){
    int i = base + tid + j*256;
    if (i < n){ t[j] = nt[i]; lr[j] = atomicAdd(&lc[t[j]], 1); }
    else t[j] = -1;
  }
  __syncthreads();
  if (tid < T_NT) lb[tid] = atomicAdd(&tcur[tid], lc[tid]);
  __syncthreads();
#pragma unroll
  for (int j=0;j<4;j++){
    if (t[j] >= 0){
      int node = base + tid + j*256;
      int pos = lb[t[j]] + lr[j];
      perm[pos] = node;
      iperm[node] = pos;
    }
  }
}

__global__ void k_deg(const int* __restrict__ dstp, const int* __restrict__ iperm,
                      int* __restrict__ degp, int* __restrict__ rank, int n){
  int i = blockIdx.x*256 + threadIdx.x;
  if (i < n) rank[i] = atomicAdd(&degp[(size_t)iperm[dstp[i]] << 4], 1);
}

__global__ void k_scanA(const int* __restrict__ degp, int* __restrict__ rp,
                        int* __restrict__ bsum, int n){
  __shared__ int buf[256];
  int tid = threadIdx.x;
  int i = blockIdx.x*256 + tid;
  int v = (i < n) ? degp[(size_t)i << 4] : 0;
  buf[tid] = v;
  __syncthreads();
  for (int off = 1; off < 256; off <<= 1){
    int add = (tid >= off) ? buf[tid - off] : 0;
    __syncthreads();
    buf[tid] += add;
    __syncthreads();
  }
  if (i < n) rp[i] = buf[tid] - v;
  if (tid == 255) bsum[blockIdx.x] = buf[255];
}
__global__ void k_scanB(int* __restrict__ bsum, int nb){
  __shared__ int buf[1024];
  int tid = threadIdx.x;
  int v = (tid < nb) ? bsum[tid] : 0;
  buf[tid] = v;
  __syncthreads();
  for (int off = 1; off < 1024; off <<= 1){
    int add = (tid >= off) ? buf[tid - off] : 0;
    __syncthreads();
    buf[tid] += add;
    __syncthreads();
  }
  if (tid < nb) bsum[tid] = buf[tid] - v;
}
__global__ void k_scanC(int* __restrict__ rp, const int* __restrict__ bsum,
                        int n, int E){
  int i = blockIdx.x*256 + threadIdx.x;
  if (i < n) rp[i] += bsum[blockIdx.x];
  if (i == 0) rp[n] = E;
}

__global__ void k_fill2(const int* __restrict__ srcp, const int* __restrict__ dstp,
                        const int* __restrict__ etp, const int* __restrict__ iperm,
                        const int* __restrict__ rp, const int* __restrict__ rank,
                        int* __restrict__ packed, int n){
  int i = blockIdx.x*256 + threadIdx.x;
  if (i < n){
    int d = iperm[dstp[i]];
    packed[rp[d] + rank[i]] = iperm[srcp[i]] | (etp[i] << 17);
  }
}

// ---------------- combined-weight prep ----------------
__global__ void k_prepmisc(const float* __restrict__ kw, const float* __restrict__ kb,
                           const float* __restrict__ qb, const float* __restrict__ vb,
                           const float* __restrict__ rel_att, const float* __restrict__ rel_msg,
                           const float* __restrict__ rel_pri,
                           u16* __restrict__ Ball, float* __restrict__ biasall)
{
  const float isd = 0.17677669529663687f;
  int idx = blockIdx.x*256 + threadIdx.x;
  if (idx < T_L*T_NT*T_HD*T_HD){
    int col = idx & 127, k = (idx >> 7) & 127, lt = idx >> 14;
    Ball[((size_t)lt*NCOL + col)*T_HD + k] = f2bf(kw[((size_t)lt*T_HD + k)*T_HD + col]);
    if (k == 0) biasall[(size_t)lt*NCOL + col] = kb[(size_t)lt*T_HD + col];
    return;
  }
  int b = idx - T_L*T_NT*T_HD*T_HD;
  if (b >= T_L*T_NT*1280) return;
  int lt = b / 1280, cc = b % 1280;
  int l = lt >> 2;
  int qv = cc >= 640, rem = cc - qv*640;
  int r = rem >> 7, hd = rem & 127, h = hd >> 5, o = hd & 31;
  float s = 0.f;
  if (!qv){
    const float* Ar = rel_att + ((((size_t)l*T_R + r)*T_H + h)*T_DK + o)*T_DK;
    const float* qbr = qb + (size_t)lt*T_HD + h*T_DK;
#pragma unroll
    for (int j = 0; j < 32; ++j) s += qbr[j] * Ar[j];
    s *= rel_pri[((size_t)l*T_R + r)*T_H + h] * isd;
  } else {
    const float* Mr = rel_msg + (((size_t)l*T_R + r)*T_H + h)*T_DK*T_DK + o;
    const float* vbr = vb + (size_t)lt*T_HD + h*T_DK;
#pragma unroll
    for (int i = 0; i < 32; ++i) s += vbr[i] * Mr[i*T_DK];
  }
  biasall[(size_t)lt*NCOL + 128 + qv*640 + r*128 + h*32 + o] = s;
}

__global__ __launch_bounds__(256)
void k_prepqv(const float* __restrict__ qw, const float* __restrict__ vw,
              const float* __restrict__ rel_att, const float* __restrict__ rel_msg,
              const float* __restrict__ rel_pri, u16* __restrict__ Ball)
{
  __shared__ float Ws[T_HD*33];
  __shared__ float As_[T_R*32*36];
  const float isd = 0.17677669529663687f;
  int h = blockIdx.x & 3, qv = blockIdx.x >> 2;
  int t = blockIdx.y, l = blockIdx.z;
  int lt = l*T_NT + t;
  int tid = threadIdx.x;
  const float* W = (qv ? vw : qw) + (size_t)lt*T_HD*T_HD;
  const float* rel = (qv ? rel_msg : rel_att);
#pragma unroll
  for (int i = 0; i < 16; ++i){
    int idx = tid + i*256;
    int j = idx & 31, k = idx >> 5;
    Ws[k*33 + j] = W[(size_t)k*T_HD + h*T_DK + j];
  }
#pragma unroll
  for (int i = 0; i < 20; ++i){
    int idx = tid + i*256;
    int bcol = idx & 31, a = (idx >> 5) & 31, r = idx >> 10;
    float wv = rel[((((size_t)l*T_R + r)*T_H + h)*T_DK + a)*T_DK + bcol];
    if (qv) As_[r*1152 + bcol*36 + a] = wv;
    else    As_[r*1152 + a*36 + bcol] = wv;
  }
  __syncthreads();
  int k = tid & 127, io = tid >> 7;
  float Wrow[32];
#pragma unroll
  for (int c = 0; c < 32; ++c) Wrow[c] = Ws[k*33 + c];
  for (int r = 0; r < T_R; ++r){
    float scale = qv ? 1.f : rel_pri[((size_t)l*T_R + r)*T_H + h] * isd;
#pragma unroll
    for (int i2 = 0; i2 < 16; ++i2){
      int o = i2*2 + io;
      const float4* ap = (const float4*)&As_[r*1152 + o*36];
      float acc = 0.f;
#pragma unroll
      for (int c4 = 0; c4 < 8; ++c4){
        float4 a4 = ap[c4];
        acc += Wrow[c4*4+0]*a4.x + Wrow[c4*4+1]*a4.y + Wrow[c4*4+2]*a4.z + Wrow[c4*4+3]*a4.w;
      }
      int col = 128 + qv*640 + r*128 + h*32 + o;
      Ball[((size_t)lt*NCOL + col)*T_HD + k] = f2bf(acc*scale);
    }
  }
}

// ---------------- fused per-type MFMA GEMM: h(bucket) -> {kB, qt, mtp}(bucket) ----------------
// chunk-pair epilogue: lane packs 4 cols of chunk c0 + 4 cols of chunk c0+1 into one 16B store.
// Memory dim order within each 32-col group is permuted (perm_l); kB/qt/mtp/resb all share it.
__global__ __launch_bounds__(256)
void k_qkvm(const float* __restrict__ X, const int* __restrict__ toff,
            const u16* __restrict__ Ball, const float* __restrict__ biasall,
            u16* __restrict__ kB, u16* __restrict__ qt, u16* __restrict__ mtp)
{
  __shared__ u16 As[64*128];
  int t = blockIdx.y;
  int z = blockIdx.z;
  int lo = toff[t], cnt = toff[t+1] - lo;
  int base = (int)blockIdx.x * 64;
  if (base >= cnt) return;
  int tid = threadIdx.x;
#pragma unroll
  for (int it = 0; it < 4; ++it){
    int chunk = tid + it*256;
    int row = chunk >> 4, c8 = (chunk & 15) << 3;
    uint4 o = make_uint4(0,0,0,0);
    if (base + row < cnt){
      const float* src = X + (size_t)(lo + base + row)*T_HD + c8;
      float4 f0 = *(const float4*)src;
      float4 f1 = *(const float4*)(src + 4);
      o.x = pk2(f0.x, f0.y);
      o.y = pk2(f0.z, f0.w);
      o.z = pk2(f1.x, f1.y);
      o.w = pk2(f1.z, f1.w);
    }
    int off16 = (row*128 + c8) ^ ((row & 7) << 3);
    *(uint4*)&As[off16] = o;
  }
  __syncthreads();

  int wid = tid >> 6, lane = tid & 63;
  int lr = lane & 15, lg = lane >> 4;
  bf8_t a[4][4];
#pragma unroll
  for (int rs = 0; rs < 4; ++rs)
#pragma unroll
    for (int kk = 0; kk < 4; ++kk){
      int row = rs*16 + lr;
      int off16 = (row*128 + kk*32 + lg*8) ^ ((row & 7) << 3);
      a[rs][kk] = *(const bf8_t*)&As[off16];
    }

  const u16* Bt = Ball + (size_t)t * NCOL * T_HD;
  const float* biast = biasall + (size_t)t * NCOL;

  // 44 chunk-pairs total; z splits them [0,22) / [22,44)
  int ci_end = z ? 44 : 22;
  for (int ci = z*22 + wid; ci < ci_end; ci += 4){
    int c0 = ci*2;
    int col0 = c0*16 + lr;
    const u16* bp0 = Bt + (size_t)col0*T_HD + lg*8;
    const u16* bp1 = bp0 + (size_t)16*T_HD;
    bf8_t b00 = *(const bf8_t*)(bp0);
    bf8_t b01 = *(const bf8_t*)(bp0 + 32);
    bf8_t b02 = *(const bf8_t*)(bp0 + 64);
    bf8_t b03 = *(const bf8_t*)(bp0 + 96);
    bf8_t b10 = *(const bf8_t*)(bp1);
    bf8_t b11 = *(const bf8_t*)(bp1 + 32);
    bf8_t b12 = *(const bf8_t*)(bp1 + 64);
    bf8_t b13 = *(const bf8_t*)(bp1 + 96);
    f4_t acc0[4], acc1[4];
#pragma unroll
    for (int rs = 0; rs < 4; ++rs){ acc0[rs] = (f4_t){0.f,0.f,0.f,0.f}; acc1[rs] = (f4_t){0.f,0.f,0.f,0.f}; }
#pragma unroll
    for (int rs = 0; rs < 4; ++rs){
      acc0[rs] = __builtin_amdgcn_mfma_f32_16x16x32_bf16(b00, a[rs][0], acc0[rs], 0, 0, 0);
      acc0[rs] = __builtin_amdgcn_mfma_f32_16x16x32_bf16(b01, a[rs][1], acc0[rs], 0, 0, 0);
      acc0[rs] = __builtin_amdgcn_mfma_f32_16x16x32_bf16(b02, a[rs][2], acc0[rs], 0, 0, 0);
      acc0[rs] = __builtin_amdgcn_mfma_f32_16x16x32_bf16(b03, a[rs][3], acc0[rs], 0, 0, 0);
      acc1[rs] = __builtin_amdgcn_mfma_f32_16x16x32_bf16(b10, a[rs][0], acc1[rs], 0, 0, 0);
      acc1[rs] = __builtin_amdgcn_mfma_f32_16x16x32_bf16(b11, a[rs][1], acc1[rs], 0, 0, 0);
      acc1[rs] = __builtin_amdgcn_mfma_f32_16x16x32_bf16(b12, a[rs][2], acc1[rs], 0, 0, 0);
      acc1[rs] = __builtin_amdgcn_mfma_f32_16x16x32_bf16(b13, a[rs][3], acc1[rs], 0, 0, 0);
    }
    float4 bias0 = *(const float4*)&biast[c0*16 + lg*4];
    float4 bias1 = *(const float4*)&biast[c0*16 + 16 + lg*4];
    int mco = ci*32 + lg*8;
    u16* dst; int cofs, stride;
    if (ci < 4)       { dst = kB;  cofs = mco;        stride = T_HD; }
    else if (ci < 24) { dst = qt;  cofs = mco - 128;  stride = T_R*T_HD; }
    else              { dst = mtp; cofs = mco - 768;  stride = T_R*T_HD; }
#pragma unroll
    for (int rs = 0; rs < 4; ++rs){
      int nl = rs*16 + lr;
      if (base + nl < cnt){
        uint4 o;
        o.x = pk2(acc0[rs][0] + bias0.x, acc0[rs][1] + bias0.y);
        o.y = pk2(acc0[rs][2] + bias0.z, acc0[rs][3] + bias0.w);
        o.z = pk2(acc1[rs][0] + bias1.x, acc1[rs][1] + bias1.y);
        o.w = pk2(acc1[rs][2] + bias1.z, acc1[rs][3] + bias1.w);
        *(uint4*)&dst[(size_t)(lo + base + nl)*stride + cofs] = o;
      }
    }
  }
}

// ---------------- per-type gathered GEMM (f32), adapt + update ----------------
// MODE 1: tanh epilogue, GIN=1 (gather X rows via tperm), linear out
// MODE 3: gelu-on-input + gated residual; X=resb has perm_l layout -> permute W k-rows; SOUT scatter
template<int MODE, int GIN, int SOUT>
__global__ __launch_bounds__(256)
void k_typed_gemm(const float* __restrict__ X,
                  const int* __restrict__ tperm, const int* __restrict__ toff,
                  const float* __restrict__ W, const float* __restrict__ Bi,
                  float* __restrict__ outv,
                  const float* __restrict__ h_in, const float* __restrict__ skipv)
{
  int t = blockIdx.y;
  int lo = toff[t], cnt = toff[t+1] - lo;
  int base = (int)blockIdx.x * 64;
  if (base >= cnt) return;
  __shared__ float As[64][16];
  __shared__ float Bs[16][128];
  __shared__ int rows_s[64];
  int tid = threadIdx.x;
  if (GIN || SOUT){
    if (tid < 64) rows_s[tid] = (base + tid < cnt) ? tperm[lo + base + tid] : -1;
    __syncthreads();
  }
  float acc[8][4];
#pragma unroll
  for (int i=0;i<8;i++){ acc[i][0]=0.f;acc[i][1]=0.f;acc[i][2]=0.f;acc[i][3]=0.f; }
  int ty = tid >> 5, tx = tid & 31;
  const float* Wt = W + (size_t)t * (T_HD*T_HD);
  for (int k0 = 0; k0 < T_HD; k0 += 16){
#pragma unroll
    for (int j=0;j<4;j++){
      int idx = tid + j*256;
      int m = idx >> 4, kk = idx & 15;
      float v = 0.f;
      if (base + m < cnt){
        if (GIN){
          int row = rows_s[m];
          v = X[(size_t)row*T_HD + k0 + kk];
        } else {
          v = X[(size_t)(lo + base + m)*T_HD + k0 + kk];
        }
        if (MODE == 3) v = gelu_f(v);
      }
      As[m][kk] = v;
    }
#pragma unroll
    for (int j=0;j<8;j++){
      int idx = tid + j*256;
      int kk = idx >> 7, c = idx & 127;
      int kg = k0 + kk;
      if (MODE == 3) kg = perm_l(kg);   // undo resb's pair-packed dim order
      Bs[kk][c] = Wt[(size_t)kg*T_HD + c];
    }
    __syncthreads();
#pragma unroll
    for (int kk=0;kk<16;kk++){
      float4 bv = *(const float4*)&Bs[kk][tx*4];
#pragma unroll
      for (int i=0;i<8;i++){
        float a = As[ty*8+i][kk];
        acc[i][0] += a*bv.x; acc[i][1] += a*bv.y; acc[i][2] += a*bv.z; acc[i][3] += a*bv.w;
      }
    }
    __syncthreads();
  }
  float sk = 0.f;
  if (MODE == 3) sk = 1.f / (1.f + __expf(-skipv[t]));
#pragma unroll
  for (int i=0;i<8;i++){
    int m = ty*8 + i;
    if (base + m >= cnt) continue;
    size_t opos = SOUT ? (size_t)rows_s[m] : (size_t)(lo + base + m);
#pragma unroll
    for (int q=0;q<4;q++){
      int c = tx*4 + q;
      float vv = acc[i][q] + Bi[t*T_HD + c];
      if (MODE == 1) vv = tanhf(vv);
      if (MODE == 3) vv = vv*sk + h_in[(size_t)(lo + base + m)*T_HD + c]*(1.f - sk);
      outv[opos*T_HD + c] = vv;
    }
  }
}

// ---------------- per-dst edge attention (dual-state online softmax) ----------------
__global__ __launch_bounds__(256)
void k_edge_attn2(const u16* __restrict__ kB, const u16* __restrict__ qt,
                  const u16* __restrict__ mtp, const int* __restrict__ rp,
                  const int* __restrict__ packed, float* __restrict__ resb, int n)
{
  int lane = threadIdx.x & 63;
  int wid = (int)blockIdx.x * (blockDim.x >> 6) + (threadIdx.x >> 6);
  int nw = (int)gridDim.x * (blockDim.x >> 6);
  int l2 = lane << 1;
  for (int dst = wid; dst < n; dst += nw){
    int e0 = rp[dst], e1 = rp[dst+1];
    if (e0 == e1){
      *(float2*)&resb[(size_t)dst*T_HD + l2] = make_float2(0.f, 0.f);
      continue;
    }
    const u16* qrow = qt + (size_t)dst*(T_R*T_HD) + l2;
    float mA=-INFINITY, dA=0.f, aA0=0.f, aA1=0.f;
    float mB=-INFINITY, dB=0.f, aB0=0.f, aB1=0.f;
    int ei = e0;
    for (; ei + 1 < e1; ei += 2){
      int pka = packed[ei], pkb = packed[ei+1];
      int sa = pka & 131071, ra = pka >> 17;
      int sb = pkb & 131071, rb = pkb >> 17;
      unsigned ka = *(const unsigned*)&kB[(sa << 7) + l2];
      unsigned kb = *(const unsigned*)&kB[(sb << 7) + l2];
      unsigned qa = *(const unsigned*)&qrow[ra << 7];
      unsigned qb = *(const unsigned*)&qrow[rb << 7];
      unsigned ma = *(const unsigned*)&mtp[((sa*T_R + ra) << 7) + l2];
      unsigned mb = *(const unsigned*)&mtp[((sb*T_R + rb) << 7) + l2];
      float pa = blo(qa)*blo(ka) + bhi(qa)*bhi(ka);
      float pb = blo(qb)*blo(kb) + bhi(qb)*bhi(kb);
      pa += __shfl_xor(pa, 1);  pb += __shfl_xor(pb, 1);
      pa += __shfl_xor(pa, 2);  pb += __shfl_xor(pb, 2);
      pa += __shfl_xor(pa, 4);  pb += __shfl_xor(pb, 4);
      pa += __shfl_xor(pa, 8);  pb += __shfl_xor(pb, 8);
      float mnA = fmaxf(mA, pa), mnB = fmaxf(mB, pb);
      float scA = __expf(mA - mnA), scB = __expf(mB - mnB);
      float wA = __expf(pa - mnA),  wB = __expf(pb - mnB);
      mA = mnA; mB = mnB;
      dA  = dA*scA + wA;          dB  = dB*scB + wB;
      aA0 = aA0*scA + wA*blo(ma); aB0 = aB0*scB + wB*blo(mb);
      aA1 = aA1*scA + wA*bhi(ma); aB1 = aB1*scB + wB*bhi(mb);
    }
    if (ei < e1){
      int pka = packed[ei];
      int sa = pka & 131071, ra = pka >> 17;
      unsigned ka = *(const unsigned*)&kB[(sa << 7) + l2];
      unsigned qa = *(const unsigned*)&qrow[ra << 7];
      unsigned ma = *(const unsigned*)&mtp[((sa*T_R + ra) << 7) + l2];
      float pa = blo(qa)*blo(ka) + bhi(qa)*bhi(ka);
      pa += __shfl_xor(pa, 1);
      pa += __shfl_xor(pa, 2);
      pa += __shfl_xor(pa, 4);
      pa += __shfl_xor(pa, 8);
      float mnA = fmaxf(mA, pa);
      float scA = __expf(mA - mnA);
      float wA = __expf(pa - mnA);
      mA = mnA;
      dA  = dA*scA + wA;
      aA0 = aA0*scA + wA*blo(ma);
      aA1 = aA1*scA + wA*bhi(ma);
    }
    // merge states (mB may be -inf when <2 edges -> exp evaluates to 0)
    float mn = fmaxf(mA, mB);
    float eA = __expf(mA - mn), eB = __expf(mB - mn);
    float d  = dA*eA + dB*eB;
    float a0 = aA0*eA + aB0*eB;
    float a1 = aA1*eA + aB1*eB;
    float inv = 1.f / fmaxf(d, 1e-9f);
    *(float2*)&resb[(size_t)dst*T_HD + l2] = make_float2(a0*inv, a1*inv);
  }
}

extern "C" void kernel_launch(void* const* d_in, const int* in_sizes, int n_in,
                              void* d_out, int out_size, void* d_ws, size_t ws_size,
                              hipStream_t stream)
{
  const float* node_feature = (const float*)d_in[0];
  const int* node_type    = (const int*)d_in[1];
  const int* edge_index   = (const int*)d_in[3];
  const int* edge_type    = (const int*)d_in[4];
  const float* adapt_w = (const float*)d_in[5];
  const float* adapt_b = (const float*)d_in[6];
  const float* kw = (const float*)d_in[7];
  const float* kb = (const float*)d_in[8];
  const float* qw = (const float*)d_in[9];
  const float* qb = (const float*)d_in[10];
  const float* vw = (const float*)d_in[11];
  const float* vb = (const float*)d_in[12];
  const float* aw = (const float*)d_in[13];
  const float* ab = (const float*)d_in[14];
  const float* rel_pri = (const float*)d_in[15];
  const float* rel_att = (const float*)d_in[16];
  const float* rel_msg = (const float*)d_in[17];
  const float* skipp   = (const float*)d_in[18];

  const int N = in_sizes[1];
  const int E = in_sizes[4];
  const int* srcp = edge_index;
  const int* dstp = edge_index + E;

  char* p = (char*)d_ws;
  auto take = [&](size_t bytes)->char*{
    char* r = p; p += (bytes + 255) & ~(size_t)255; return r;
  };
  float* h0   = (float*)take((size_t)N*T_HD*4);
  float* resb = (float*)take((size_t)N*T_HD*4);
  u16*  kB    = (u16*) take((size_t)N*T_HD*2);
  u16*  qt    = (u16*) take((size_t)N*T_R*T_HD*2);
  u16*  mtp   = (u16*) take((size_t)N*T_R*T_HD*2);
  u16*  Ball  = (u16*) take((size_t)T_L*T_NT*NCOL*T_HD*2);
  float* biasall = (float*)take((size_t)T_L*T_NT*NCOL*4);
  int* degp   = (int*) take((size_t)N*16*4);
  int* rp     = (int*) take(((size_t)N+1)*4);
  int* rank   = (int*) take((size_t)E*4);
  int* packed = (int*) take((size_t)E*4);
  int* tcnt   = (int*) take(256);
  int* toff   = (int*) take(256);
  int* tcur   = (int*) take(256);
  int* bsum   = (int*) take(1024);
  int* tperm  = (int*) take((size_t)N*4);
  int* iperm  = (int*) take((size_t)N*4);

  hipMemsetAsync(degp, 0, (size_t)N*16*4, stream);
  hipMemsetAsync(tcnt, 0, 256, stream);

  int nb_n4 = (N + 1023)/1024, nb_e = (E + 255)/256;
  int nb_s  = (N + 255)/256;
  k_hist4<<<nb_n4, 256, 0, stream>>>(node_type, tcnt, N);
  k_toff<<<1, 64, 0, stream>>>(tcnt, toff, tcur);
  k_scatter2<<<nb_n4, 256, 0, stream>>>(node_type, tcur, tperm, iperm, N);
  k_deg<<<nb_e, 256, 0, stream>>>(dstp, iperm, degp, rank, E);
  k_scanA<<<nb_s, 256, 0, stream>>>(degp, rp, bsum, N);
  k_scanB<<<1, 1024, 0, stream>>>(bsum, nb_s);
  k_scanC<<<nb_s, 256, 0, stream>>>(rp, bsum, N, E);
  k_fill2<<<nb_e, 256, 0, stream>>>(srcp, dstp, edge_type, iperm, rp, rank, packed, E);

  int misc_total = T_L*T_NT*T_HD*T_HD + T_L*T_NT*1280;
  k_prepmisc<<<(misc_total + 255)/256, 256, 0, stream>>>(
      kw, kb, qb, vb, rel_att, rel_msg, rel_pri, Ball, biasall);
  k_prepqv<<<dim3(8, T_NT, T_L), 256, 0, stream>>>(
      qw, vw, rel_att, rel_msg, rel_pri, Ball);

  dim3 gg((N + 63)/64, T_NT);
  dim3 gq((N + 63)/64, T_NT, 2);
  k_typed_gemm<1,1,0><<<gg, 256, 0, stream>>>(node_feature, tperm, toff, adapt_w, adapt_b, h0, nullptr, nullptr);

  for (int l = 0; l < T_L; ++l){
    size_t wo = (size_t)l * T_NT * T_HD * T_HD;
    size_t bo = (size_t)l * T_NT * T_HD;
    k_qkvm<<<gq, 256, 0, stream>>>(h0, toff,
        Ball + (size_t)l*T_NT*NCOL*T_HD, biasall + (size_t)l*T_NT*NCOL,
        kB, qt, mtp);
    k_edge_attn2<<<2048, 256, 0, stream>>>(kB, qt, mtp, rp, packed, resb, N);
    if (l == T_L - 1)
      k_typed_gemm<3,0,1><<<gg, 256, 0, stream>>>(resb, tperm, toff, aw+wo, ab+bo,
          (float*)d_out, h0, skipp + l*T_NT);
    else
      k_typed_gemm<3,0,0><<<gg, 256, 0, stream>>>(resb, tperm, toff, aw+wo, ab+bo,
          h0, h0, skipp + l*T_NT);
  }
}

// Round 11
// 392.933 us; speedup vs baseline: 22.2119x; 1.1723x over previous
//
#include <hip/hip_runtime.h>

#define T_NT 4
#define T_R  5
#define T_H  4
#define T_DK 32
#define T_HD 128
#define T_L  2
#define NCOL 1408   // 128 (k) + 640 (qt) + 640 (mtp)

typedef unsigned short u16;
typedef __bf16 bf8_t __attribute__((ext_vector_type(8)));
typedef float f4_t __attribute__((ext_vector_type(4)));

__device__ __forceinline__ float bf2f(u16 u){
  union { float f; unsigned int i; } v; v.i = ((unsigned int)u) << 16; return v.f;
}
__device__ __forceinline__ float blo(unsigned u){
  union { float f; unsigned int i; } v; v.i = u << 16; return v.f;
}
__device__ __forceinline__ float bhi(unsigned u){
  union { float f; unsigned int i; } v; v.i = u & 0xffff0000u; return v.f;
}
__device__ __forceinline__ u16 f2bf(float f){
  union { float f; unsigned int i; } v; v.f = f;
  unsigned int x = v.i;
  return (u16)((x + 0x7fffu + ((x >> 16) & 1u)) >> 16);
}
__device__ __forceinline__ unsigned pk2(float a, float b){
  return (unsigned)f2bf(a) | ((unsigned)f2bf(b) << 16);
}
__device__ __forceinline__ float gelu_f(float x){
  float x3 = x*x*x;
  return 0.5f * x * (1.f + tanhf(0.7978845608028654f * (x + 0.044715f * x3)));
}
// mem-position -> logical col for the pair-packed layout (see k_qkvm epilogue)
__device__ __forceinline__ int perm_l(int m){
  return (m & ~31) | ((m & 4) << 2) | ((m & 24) >> 1) | (m & 3);
}

// ---------------- CSR / bucket build ----------------
__global__ void k_hist4(const int* __restrict__ key, int* __restrict__ cnt, int n){
  __shared__ int c[T_NT];
  int tid = threadIdx.x;
  if (tid < T_NT) c[tid] = 0;
  __syncthreads();
  int base = blockIdx.x*1024;
#pragma unroll
  for (int j=0;j<4;j++){
    int i = base + tid + j*256;
    if (i < n) atomicAdd(&c[key[i]], 1);
  }
  __syncthreads();
  if (tid < T_NT) atomicAdd(&cnt[tid], c[tid]);
}

__global__ void k_toff(const int* __restrict__ cnt, int* __restrict__ off, int* __restrict__ tcur){
  if (threadIdx.x == 0){
    off[0] = 0;
    for (int t = 0; t < T_NT; ++t) off[t+1] = off[t] + cnt[t];
    for (int t = 0; t < T_NT; ++t) tcur[t] = off[t];
  }
}

__global__ void k_scatter2(const int* __restrict__ nt, int* __restrict__ tcur,
                           int* __restrict__ perm, int* __restrict__ iperm, int n){
  __shared__ int lc[T_NT], lb[T_NT];
  int tid = threadIdx.x;
  if (tid < T_NT) lc[tid] = 0;
  __syncthreads();
  int base = blockIdx.x*1024;
  int t[4], lr[4];
#pragma unroll
  for (int j=0;j<4;j++){
    int i = base + tid + j*256;
    if (i < n){ t[j] = nt[i]; lr[j] = atomicAdd(&lc[t[j]], 1); }
    else t[j] = -1;
  }
  __syncthreads();
  if (tid < T_NT) lb[tid] = atomicAdd(&tcur[tid], lc[tid]);
  __syncthreads();
#pragma unroll
  for (int j=0;j<4;j++){
    if (t[j] >= 0){
      int node = base + tid + j*256;
      int pos = lb[t[j]] + lr[j];
      perm[pos] = node;
      iperm[node] = pos;
    }
  }
}

__global__ void k_deg(const int* __restrict__ dstp, const int* __restrict__ iperm,
                      int* __restrict__ degp, int* __restrict__ rank, int n){
  int i = blockIdx.x*256 + threadIdx.x;
  if (i < n) rank[i] = atomicAdd(&degp[(size_t)iperm[dstp[i]] << 4], 1);
}

__global__ void k_scanA(const int* __restrict__ degp, int* __restrict__ rp,
                        int* __restrict__ bsum, int n){
  __shared__ int buf[256];
  int tid = threadIdx.x;
  int i = blockIdx.x*256 + tid;
  int v = (i < n) ? degp[(size_t)i << 4] : 0;
  buf[tid] = v;
  __syncthreads();
  for (int off = 1; off < 256; off <<= 1){
    int add = (tid >= off) ? buf[tid - off] : 0;
    __syncthreads();
    buf[tid] += add;
    __syncthreads();
  }
  if (i < n) rp[i] = buf[tid] - v;
  if (tid == 255) bsum[blockIdx.x] = buf[255];
}
__global__ void k_scanB(int* __restrict__ bsum, int nb){
  __shared__ int buf[1024];
  int tid = threadIdx.x;
  int v = (tid < nb) ? bsum[tid] : 0;
  buf[tid] = v;
  __syncthreads();
  for (int off = 1; off < 1024; off <<= 1){
    int add = (tid >= off) ? buf[tid - off] : 0;
    __syncthreads();
    buf[tid] += add;
    __syncthreads();
  }
  if (tid < nb) bsum[tid] = buf[tid] - v;
}
__global__ void k_scanC(int* __restrict__ rp, const int* __restrict__ bsum,
                        int n, int E){
  int i = blockIdx.x*256 + threadIdx.x;
  if (i < n) rp[i] += bsum[blockIdx.x];
  if (i == 0) rp[n] = E;
}

__global__ void k_fill2(const int* __restrict__ srcp, const int* __restrict__ dstp,
                        const int* __restrict__ etp, const int* __restrict__ iperm,
                        const int* __restrict__ rp, const int* __restrict__ rank,
                        int* __restrict__ packed, int n){
  int i = blockIdx.x*256 + threadIdx.x;
  if (i < n){
    int d = iperm[dstp[i]];
    packed[rp[d] + rank[i]] = iperm[srcp[i]] | (etp[i] << 17);
  }
}

// ---------------- combined-weight prep ----------------
__global__ void k_prepmisc(const float* __restrict__ kw, const float* __restrict__ kb,
                           const float* __restrict__ qb, const float* __restrict__ vb,
                           const float* __restrict__ rel_att, const float* __restrict__ rel_msg,
                           const float* __restrict__ rel_pri,
                           u16* __restrict__ Ball, float* __restrict__ biasall)
{
  const float isd = 0.17677669529663687f;
  int idx = blockIdx.x*256 + threadIdx.x;
  if (idx < T_L*T_NT*T_HD*T_HD){
    int col = idx & 127, k = (idx >> 7) & 127, lt = idx >> 14;
    Ball[((size_t)lt*NCOL + col)*T_HD + k] = f2bf(kw[((size_t)lt*T_HD + k)*T_HD + col]);
    if (k == 0) biasall[(size_t)lt*NCOL + col] = kb[(size_t)lt*T_HD + col];
    return;
  }
  int b = idx - T_L*T_NT*T_HD*T_HD;
  if (b >= T_L*T_NT*1280) return;
  int lt = b / 1280, cc = b % 1280;
  int l = lt >> 2;
  int qv = cc >= 640, rem = cc - qv*640;
  int r = rem >> 7, hd = rem & 127, h = hd >> 5, o = hd & 31;
  float s = 0.f;
  if (!qv){
    const float* Ar = rel_att + ((((size_t)l*T_R + r)*T_H + h)*T_DK + o)*T_DK;
    const float* qbr = qb + (size_t)lt*T_HD + h*T_DK;
#pragma unroll
    for (int j = 0; j < 32; ++j) s += qbr[j] * Ar[j];
    s *= rel_pri[((size_t)l*T_R + r)*T_H + h] * isd;
  } else {
    const float* Mr = rel_msg + (((size_t)l*T_R + r)*T_H + h)*T_DK*T_DK + o;
    const float* vbr = vb + (size_t)lt*T_HD + h*T_DK;
#pragma unroll
    for (int i = 0; i < 32; ++i) s += vbr[i] * Mr[i*T_DK];
  }
  biasall[(size_t)lt*NCOL + 128 + qv*640 + r*128 + h*32 + o] = s;
}

__global__ __launch_bounds__(256)
void k_prepqv(const float* __restrict__ qw, const float* __restrict__ vw,
              const float* __restrict__ rel_att, const float* __restrict__ rel_msg,
              const float* __restrict__ rel_pri, u16* __restrict__ Ball)
{
  __shared__ float Ws[T_HD*33];
  __shared__ float As_[T_R*32*36];
  const float isd = 0.17677669529663687f;
  int h = blockIdx.x & 3, qv = blockIdx.x >> 2;
  int t = blockIdx.y, l = blockIdx.z;
  int lt = l*T_NT + t;
  int tid = threadIdx.x;
  const float* W = (qv ? vw : qw) + (size_t)lt*T_HD*T_HD;
  const float* rel = (qv ? rel_msg : rel_att);
#pragma unroll
  for (int i = 0; i < 16; ++i){
    int idx = tid + i*256;
    int j = idx & 31, k = idx >> 5;
    Ws[k*33 + j] = W[(size_t)k*T_HD + h*T_DK + j];
  }
#pragma unroll
  for (int i = 0; i < 20; ++i){
    int idx = tid + i*256;
    int bcol = idx & 31, a = (idx >> 5) & 31, r = idx >> 10;
    float wv = rel[((((size_t)l*T_R + r)*T_H + h)*T_DK + a)*T_DK + bcol];
    if (qv) As_[r*1152 + bcol*36 + a] = wv;
    else    As_[r*1152 + a*36 + bcol] = wv;
  }
  __syncthreads();
  int k = tid & 127, io = tid >> 7;
  float Wrow[32];
#pragma unroll
  for (int c = 0; c < 32; ++c) Wrow[c] = Ws[k*33 + c];
  for (int r = 0; r < T_R; ++r){
    float scale = qv ? 1.f : rel_pri[((size_t)l*T_R + r)*T_H + h] * isd;
#pragma unroll
    for (int i2 = 0; i2 < 16; ++i2){
      int o = i2*2 + io;
      const float4* ap = (const float4*)&As_[r*1152 + o*36];
      float acc = 0.f;
#pragma unroll
      for (int c4 = 0; c4 < 8; ++c4){
        float4 a4 = ap[c4];
        acc += Wrow[c4*4+0]*a4.x + Wrow[c4*4+1]*a4.y + Wrow[c4*4+2]*a4.z + Wrow[c4*4+3]*a4.w;
      }
      int col = 128 + qv*640 + r*128 + h*32 + o;
      Ball[((size_t)lt*NCOL + col)*T_HD + k] = f2bf(acc*scale);
    }
  }
}

// bf16 transposed weights for the FFN MFMA kernels
// adaptT[t][col][k] = adapt_w[t][k][col]; awT[lt][col][k] = aw[lt][perm_l(k)][col]
__global__ void k_prepw2(const float* __restrict__ adapt_w, const float* __restrict__ aw,
                         u16* __restrict__ adaptT, u16* __restrict__ awT)
{
  int idx = blockIdx.x*256 + threadIdx.x;
  if (idx < T_NT*T_HD*T_HD){
    int k = idx & 127, col = (idx >> 7) & 127, t = idx >> 14;
    adaptT[idx] = f2bf(adapt_w[((size_t)t*T_HD + k)*T_HD + col]);
  } else {
    int j = idx - T_NT*T_HD*T_HD;
    if (j >= T_L*T_NT*T_HD*T_HD) return;
    int k = j & 127, col = (j >> 7) & 127, lt = j >> 14;
    awT[j] = f2bf(aw[((size_t)lt*T_HD + perm_l(k))*T_HD + col]);
  }
}

// ---------------- fused per-type MFMA GEMM: h(bucket) -> {kB, qt, mtp}(bucket) ----------------
__global__ __launch_bounds__(256)
void k_qkvm(const float* __restrict__ X, const int* __restrict__ toff,
            const u16* __restrict__ Ball, const float* __restrict__ biasall,
            u16* __restrict__ kB, u16* __restrict__ qt, u16* __restrict__ mtp)
{
  __shared__ u16 As[64*128];
  int t = blockIdx.y;
  int z = blockIdx.z;
  int lo = toff[t], cnt = toff[t+1] - lo;
  int base = (int)blockIdx.x * 64;
  if (base >= cnt) return;
  int tid = threadIdx.x;
#pragma unroll
  for (int it = 0; it < 4; ++it){
    int chunk = tid + it*256;
    int row = chunk >> 4, c8 = (chunk & 15) << 3;
    uint4 o = make_uint4(0,0,0,0);
    if (base + row < cnt){
      const float* src = X + (size_t)(lo + base + row)*T_HD + c8;
      float4 f0 = *(const float4*)src;
      float4 f1 = *(const float4*)(src + 4);
      o.x = pk2(f0.x, f0.y);
      o.y = pk2(f0.z, f0.w);
      o.z = pk2(f1.x, f1.y);
      o.w = pk2(f1.z, f1.w);
    }
    int off16 = (row*128 + c8) ^ ((row & 7) << 3);
    *(uint4*)&As[off16] = o;
  }
  __syncthreads();

  int wid = tid >> 6, lane = tid & 63;
  int lr = lane & 15, lg = lane >> 4;
  bf8_t a[4][4];
#pragma unroll
  for (int rs = 0; rs < 4; ++rs)
#pragma unroll
    for (int kk = 0; kk < 4; ++kk){
      int row = rs*16 + lr;
      int off16 = (row*128 + kk*32 + lg*8) ^ ((row & 7) << 3);
      a[rs][kk] = *(const bf8_t*)&As[off16];
    }

  const u16* Bt = Ball + (size_t)t * NCOL * T_HD;
  const float* biast = biasall + (size_t)t * NCOL;

  int ci_end = z ? 44 : 22;
  for (int ci = z*22 + wid; ci < ci_end; ci += 4){
    int c0 = ci*2;
    int col0 = c0*16 + lr;
    const u16* bp0 = Bt + (size_t)col0*T_HD + lg*8;
    const u16* bp1 = bp0 + (size_t)16*T_HD;
    bf8_t b00 = *(const bf8_t*)(bp0);
    bf8_t b01 = *(const bf8_t*)(bp0 + 32);
    bf8_t b02 = *(const bf8_t*)(bp0 + 64);
    bf8_t b03 = *(const bf8_t*)(bp0 + 96);
    bf8_t b10 = *(const bf8_t*)(bp1);
    bf8_t b11 = *(const bf8_t*)(bp1 + 32);
    bf8_t b12 = *(const bf8_t*)(bp1 + 64);
    bf8_t b13 = *(const bf8_t*)(bp1 + 96);
    f4_t acc0[4], acc1[4];
#pragma unroll
    for (int rs = 0; rs < 4; ++rs){ acc0[rs] = (f4_t){0.f,0.f,0.f,0.f}; acc1[rs] = (f4_t){0.f,0.f,0.f,0.f}; }
#pragma unroll
    for (int rs = 0; rs < 4; ++rs){
      acc0[rs] = __builtin_amdgcn_mfma_f32_16x16x32_bf16(b00, a[rs][0], acc0[rs], 0, 0, 0);
      acc0[rs] = __builtin_amdgcn_mfma_f32_16x16x32_bf16(b01, a[rs][1], acc0[rs], 0, 0, 0);
      acc0[rs] = __builtin_amdgcn_mfma_f32_16x16x32_bf16(b02, a[rs][2], acc0[rs], 0, 0, 0);
      acc0[rs] = __builtin_amdgcn_mfma_f32_16x16x32_bf16(b03, a[rs][3], acc0[rs], 0, 0, 0);
      acc1[rs] = __builtin_amdgcn_mfma_f32_16x16x32_bf16(b10, a[rs][0], acc1[rs], 0, 0, 0);
      acc1[rs] = __builtin_amdgcn_mfma_f32_16x16x32_bf16(b11, a[rs][1], acc1[rs], 0, 0, 0);
      acc1[rs] = __builtin_amdgcn_mfma_f32_16x16x32_bf16(b12, a[rs][2], acc1[rs], 0, 0, 0);
      acc1[rs] = __builtin_amdgcn_mfma_f32_16x16x32_bf16(b13, a[rs][3], acc1[rs], 0, 0, 0);
    }
    float4 bias0 = *(const float4*)&biast[c0*16 + lg*4];
    float4 bias1 = *(const float4*)&biast[c0*16 + 16 + lg*4];
    int mco = ci*32 + lg*8;
    u16* dst; int cofs, stride;
    if (ci < 4)       { dst = kB;  cofs = mco;        stride = T_HD; }
    else if (ci < 24) { dst = qt;  cofs = mco - 128;  stride = T_R*T_HD; }
    else              { dst = mtp; cofs = mco - 768;  stride = T_R*T_HD; }
#pragma unroll
    for (int rs = 0; rs < 4; ++rs){
      int nl = rs*16 + lr;
      if (base + nl < cnt){
        uint4 o;
        o.x = pk2(acc0[rs][0] + bias0.x, acc0[rs][1] + bias0.y);
        o.y = pk2(acc0[rs][2] + bias0.z, acc0[rs][3] + bias0.w);
        o.z = pk2(acc1[rs][0] + bias1.x, acc1[rs][1] + bias1.y);
        o.w = pk2(acc1[rs][2] + bias1.z, acc1[rs][3] + bias1.w);
        *(uint4*)&dst[(size_t)(lo + base + nl)*stride + cofs] = o;
      }
    }
  }
}

// ---------------- MFMA FFN: adapt (MODE 1) and update (MODE 3) ----------------
// MODE 1: out = tanh(X@W + b), GIN: gather X rows via tperm
// MODE 3: out = (gelu(X)@W + b)*sk + h_in*(1-sk); X in perm_l layout, W pre-permuted (awT)
template<int MODE, int GIN, int SOUT>
__global__ __launch_bounds__(256)
void k_ffn(const float* __restrict__ X, const int* __restrict__ tperm,
           const int* __restrict__ toff, const u16* __restrict__ WT,
           const float* __restrict__ Bi, float* __restrict__ outv,
           const float* __restrict__ h_in, const float* __restrict__ skipv)
{
  __shared__ u16 As[64*128];
  __shared__ int rows_s[64];
  int t = blockIdx.y;
  int lo = toff[t], cnt = toff[t+1] - lo;
  int base = (int)blockIdx.x * 64;
  if (base >= cnt) return;
  int tid = threadIdx.x;
  if (GIN || SOUT){
    if (tid < 64) rows_s[tid] = (base + tid < cnt) ? tperm[lo + base + tid] : 0;
    __syncthreads();
  }
#pragma unroll
  for (int it = 0; it < 4; ++it){
    int chunk = tid + it*256;
    int row = chunk >> 4, c8 = (chunk & 15) << 3;
    uint4 o = make_uint4(0,0,0,0);
    if (base + row < cnt){
      const float* src = GIN ? (X + (size_t)rows_s[row]*T_HD + c8)
                             : (X + (size_t)(lo + base + row)*T_HD + c8);
      float4 f0 = *(const float4*)src;
      float4 f1 = *(const float4*)(src + 4);
      if (MODE == 3){
        f0.x = gelu_f(f0.x); f0.y = gelu_f(f0.y); f0.z = gelu_f(f0.z); f0.w = gelu_f(f0.w);
        f1.x = gelu_f(f1.x); f1.y = gelu_f(f1.y); f1.z = gelu_f(f1.z); f1.w = gelu_f(f1.w);
      }
      o.x = pk2(f0.x, f0.y);
      o.y = pk2(f0.z, f0.w);
      o.z = pk2(f1.x, f1.y);
      o.w = pk2(f1.z, f1.w);
    }
    int off16 = (row*128 + c8) ^ ((row & 7) << 3);
    *(uint4*)&As[off16] = o;
  }
  __syncthreads();

  int wid = tid >> 6, lane = tid & 63;
  int lr = lane & 15, lg = lane >> 4;
  bf8_t a[4][4];
#pragma unroll
  for (int rs = 0; rs < 4; ++rs)
#pragma unroll
    for (int kk = 0; kk < 4; ++kk){
      int row = rs*16 + lr;
      int off16 = (row*128 + kk*32 + lg*8) ^ ((row & 7) << 3);
      a[rs][kk] = *(const bf8_t*)&As[off16];
    }

  const u16* Wt = WT + (size_t)t * T_HD * T_HD;
  float sk = 0.f;
  if (MODE == 3) sk = 1.f / (1.f + __expf(-skipv[t]));

  for (int c = wid; c < 8; c += 4){
    const u16* bp = Wt + (size_t)(c*16 + lr)*T_HD + lg*8;
    bf8_t b0 = *(const bf8_t*)(bp);
    bf8_t b1 = *(const bf8_t*)(bp + 32);
    bf8_t b2 = *(const bf8_t*)(bp + 64);
    bf8_t b3 = *(const bf8_t*)(bp + 96);
    f4_t acc[4];
#pragma unroll
    for (int rs = 0; rs < 4; ++rs) acc[rs] = (f4_t){0.f,0.f,0.f,0.f};
#pragma unroll
    for (int rs = 0; rs < 4; ++rs){
      acc[rs] = __builtin_amdgcn_mfma_f32_16x16x32_bf16(b0, a[rs][0], acc[rs], 0, 0, 0);
      acc[rs] = __builtin_amdgcn_mfma_f32_16x16x32_bf16(b1, a[rs][1], acc[rs], 0, 0, 0);
      acc[rs] = __builtin_amdgcn_mfma_f32_16x16x32_bf16(b2, a[rs][2], acc[rs], 0, 0, 0);
      acc[rs] = __builtin_amdgcn_mfma_f32_16x16x32_bf16(b3, a[rs][3], acc[rs], 0, 0, 0);
    }
    int cc = c*16 + lg*4;
    float4 bias4 = *(const float4*)&Bi[t*T_HD + cc];
#pragma unroll
    for (int rs = 0; rs < 4; ++rs){
      int nl = rs*16 + lr;
      if (base + nl < cnt){
        float4 vv;
        vv.x = acc[rs][0] + bias4.x;
        vv.y = acc[rs][1] + bias4.y;
        vv.z = acc[rs][2] + bias4.z;
        vv.w = acc[rs][3] + bias4.w;
        if (MODE == 1){
          vv.x = tanhf(vv.x); vv.y = tanhf(vv.y); vv.z = tanhf(vv.z); vv.w = tanhf(vv.w);
        }
        if (MODE == 3){
          float4 hr = *(const float4*)&h_in[(size_t)(lo + base + nl)*T_HD + cc];
          float osk = 1.f - sk;
          vv.x = vv.x*sk + hr.x*osk;
          vv.y = vv.y*sk + hr.y*osk;
          vv.z = vv.z*sk + hr.z*osk;
          vv.w = vv.w*sk + hr.w*osk;
        }
        size_t opos = SOUT ? (size_t)rows_s[nl] : (size_t)(lo + base + nl);
        *(float4*)&outv[opos*T_HD + cc] = vv;
      }
    }
  }
}

// ---------------- per-dst edge attention (dual-state online softmax) ----------------
__global__ __launch_bounds__(256)
void k_edge_attn2(const u16* __restrict__ kB, const u16* __restrict__ qt,
                  const u16* __restrict__ mtp, const int* __restrict__ rp,
                  const int* __restrict__ packed, float* __restrict__ resb, int n)
{
  int lane = threadIdx.x & 63;
  int wid = (int)blockIdx.x * (blockDim.x >> 6) + (threadIdx.x >> 6);
  int nw = (int)gridDim.x * (blockDim.x >> 6);
  int l2 = lane << 1;
  for (int dst = wid; dst < n; dst += nw){
    int e0 = rp[dst], e1 = rp[dst+1];
    if (e0 == e1){
      *(float2*)&resb[(size_t)dst*T_HD + l2] = make_float2(0.f, 0.f);
      continue;
    }
    const u16* qrow = qt + (size_t)dst*(T_R*T_HD) + l2;
    float mA=-INFINITY, dA=0.f, aA0=0.f, aA1=0.f;
    float mB=-INFINITY, dB=0.f, aB0=0.f, aB1=0.f;
    int ei = e0;
    for (; ei + 1 < e1; ei += 2){
      int pka = packed[ei], pkb = packed[ei+1];
      int sa = pka & 131071, ra = pka >> 17;
      int sb = pkb & 131071, rb = pkb >> 17;
      unsigned ka = *(const unsigned*)&kB[(sa << 7) + l2];
      unsigned kb = *(const unsigned*)&kB[(sb << 7) + l2];
      unsigned qa = *(const unsigned*)&qrow[ra << 7];
      unsigned qb = *(const unsigned*)&qrow[rb << 7];
      unsigned ma = *(const unsigned*)&mtp[((sa*T_R + ra) << 7) + l2];
      unsigned mb = *(const unsigned*)&mtp[((sb*T_R + rb) << 7) + l2];
      float pa = blo(qa)*blo(ka) + bhi(qa)*bhi(ka);
      float pb = blo(qb)*blo(kb) + bhi(qb)*bhi(kb);
      pa += __shfl_xor(pa, 1);  pb += __shfl_xor(pb, 1);
      pa += __shfl_xor(pa, 2);  pb += __shfl_xor(pb, 2);
      pa += __shfl_xor(pa, 4);  pb += __shfl_xor(pb, 4);
      pa += __shfl_xor(pa, 8);  pb += __shfl_xor(pb, 8);
      float mnA = fmaxf(mA, pa), mnB = fmaxf(mB, pb);
      float scA = __expf(mA - mnA), scB = __expf(mB - mnB);
      float wA = __expf(pa - mnA),  wB = __expf(pb - mnB);
      mA = mnA; mB = mnB;
      dA  = dA*scA + wA;          dB  = dB*scB + wB;
      aA0 = aA0*scA + wA*blo(ma); aB0 = aB0*scB + wB*blo(mb);
      aA1 = aA1*scA + wA*bhi(ma); aB1 = aB1*scB + wB*bhi(mb);
    }
    if (ei < e1){
      int pka = packed[ei];
      int sa = pka & 131071, ra = pka >> 17;
      unsigned ka = *(const unsigned*)&kB[(sa << 7) + l2];
      unsigned qa = *(const unsigned*)&qrow[ra << 7];
      unsigned ma = *(const unsigned*)&mtp[((sa*T_R + ra) << 7) + l2];
      float pa = blo(qa)*blo(ka) + bhi(qa)*bhi(ka);
      pa += __shfl_xor(pa, 1);
      pa += __shfl_xor(pa, 2);
      pa += __shfl_xor(pa, 4);
      pa += __shfl_xor(pa, 8);
      float mnA = fmaxf(mA, pa);
      float scA = __expf(mA - mnA);
      float wA = __expf(pa - mnA);
      mA = mnA;
      dA  = dA*scA + wA;
      aA0 = aA0*scA + wA*blo(ma);
      aA1 = aA1*scA + wA*bhi(ma);
    }
    float mn = fmaxf(mA, mB);
    float eA = __expf(mA - mn), eB = __expf(mB - mn);
    float d  = dA*eA + dB*eB;
    float a0 = aA0*eA + aB0*eB;
    float a1 = aA1*eA + aB1*eB;
    float inv = 1.f / fmaxf(d, 1e-9f);
    *(float2*)&resb[(size_t)dst*T_HD + l2] = make_float2(a0*inv, a1*inv);
  }
}

extern "C" void kernel_launch(void* const* d_in, const int* in_sizes, int n_in,
                              void* d_out, int out_size, void* d_ws, size_t ws_size,
                              hipStream_t stream)
{
  const float* node_feature = (const float*)d_in[0];
  const int* node_type    = (const int*)d_in[1];
  const int* edge_index   = (const int*)d_in[3];
  const int* edge_type    = (const int*)d_in[4];
  const float* adapt_w = (const float*)d_in[5];
  const float* adapt_b = (const float*)d_in[6];
  const float* kw = (const float*)d_in[7];
  const float* kb = (const float*)d_in[8];
  const float* qw = (const float*)d_in[9];
  const float* qb = (const float*)d_in[10];
  const float* vw = (const float*)d_in[11];
  const float* vb = (const float*)d_in[12];
  const float* aw = (const float*)d_in[13];
  const float* ab = (const float*)d_in[14];
  const float* rel_pri = (const float*)d_in[15];
  const float* rel_att = (const float*)d_in[16];
  const float* rel_msg = (const float*)d_in[17];
  const float* skipp   = (const float*)d_in[18];

  const int N = in_sizes[1];
  const int E = in_sizes[4];
  const int* srcp = edge_index;
  const int* dstp = edge_index + E;

  char* p = (char*)d_ws;
  auto take = [&](size_t bytes)->char*{
    char* r = p; p += (bytes + 255) & ~(size_t)255; return r;
  };
  float* h0   = (float*)take((size_t)N*T_HD*4);
  float* resb = (float*)take((size_t)N*T_HD*4);
  u16*  kB    = (u16*) take((size_t)N*T_HD*2);
  u16*  qt    = (u16*) take((size_t)N*T_R*T_HD*2);
  u16*  mtp   = (u16*) take((size_t)N*T_R*T_HD*2);
  u16*  Ball  = (u16*) take((size_t)T_L*T_NT*NCOL*T_HD*2);
  float* biasall = (float*)take((size_t)T_L*T_NT*NCOL*4);
  u16*  adaptT = (u16*)take((size_t)T_NT*T_HD*T_HD*2);
  u16*  awT    = (u16*)take((size_t)T_L*T_NT*T_HD*T_HD*2);
  int* degp   = (int*) take((size_t)N*16*4);
  int* rp     = (int*) take(((size_t)N+1)*4);
  int* rank   = (int*) take((size_t)E*4);
  int* packed = (int*) take((size_t)E*4);
  int* tcnt   = (int*) take(256);
  int* toff   = (int*) take(256);
  int* tcur   = (int*) take(256);
  int* bsum   = (int*) take(1024);
  int* tperm  = (int*) take((size_t)N*4);
  int* iperm  = (int*) take((size_t)N*4);

  hipMemsetAsync(degp, 0, (size_t)N*16*4, stream);
  hipMemsetAsync(tcnt, 0, 256, stream);

  int nb_n4 = (N + 1023)/1024, nb_e = (E + 255)/256;
  int nb_s  = (N + 255)/256;
  k_hist4<<<nb_n4, 256, 0, stream>>>(node_type, tcnt, N);
  k_toff<<<1, 64, 0, stream>>>(tcnt, toff, tcur);
  k_scatter2<<<nb_n4, 256, 0, stream>>>(node_type, tcur, tperm, iperm, N);
  k_deg<<<nb_e, 256, 0, stream>>>(dstp, iperm, degp, rank, E);
  k_scanA<<<nb_s, 256, 0, stream>>>(degp, rp, bsum, N);
  k_scanB<<<1, 1024, 0, stream>>>(bsum, nb_s);
  k_scanC<<<nb_s, 256, 0, stream>>>(rp, bsum, N, E);
  k_fill2<<<nb_e, 256, 0, stream>>>(srcp, dstp, edge_type, iperm, rp, rank, packed, E);

  int misc_total = T_L*T_NT*T_HD*T_HD + T_L*T_NT*1280;
  k_prepmisc<<<(misc_total + 255)/256, 256, 0, stream>>>(
      kw, kb, qb, vb, rel_att, rel_msg, rel_pri, Ball, biasall);
  k_prepqv<<<dim3(8, T_NT, T_L), 256, 0, stream>>>(
      qw, vw, rel_att, rel_msg, rel_pri, Ball);
  int w2_total = T_NT*T_HD*T_HD + T_L*T_NT*T_HD*T_HD;
  k_prepw2<<<(w2_total + 255)/256, 256, 0, stream>>>(adapt_w, aw, adaptT, awT);

  dim3 gg((N + 63)/64, T_NT);
  dim3 gq((N + 63)/64, T_NT, 2);
  k_ffn<1,1,0><<<gg, 256, 0, stream>>>(node_feature, tperm, toff, adaptT, adapt_b, h0, nullptr, nullptr);

  for (int l = 0; l < T_L; ++l){
    size_t bo = (size_t)l * T_NT * T_HD;
    k_qkvm<<<gq, 256, 0, stream>>>(h0, toff,
        Ball + (size_t)l*T_NT*NCOL*T_HD, biasall + (size_t)l*T_NT*NCOL,
        kB, qt, mtp);
    k_edge_attn2<<<2048, 256, 0, stream>>>(kB, qt, mtp, rp, packed, resb, N);
    if (l == T_L - 1)
      k_ffn<3,0,1><<<gg, 256, 0, stream>>>(resb, tperm, toff,
          awT + (size_t)l*T_NT*T_HD*T_HD, ab + bo, (float*)d_out, h0, skipp + l*T_NT);
    else
      k_ffn<3,0,0><<<gg, 256, 0, stream>>>(resb, tperm, toff,
          awT + (size_t)l*T_NT*T_HD*T_HD, ab + bo, h0, h0, skipp + l*T_NT);
  }
}